// Round 1
// baseline (3057.982 us; speedup 1.0000x reference)
//
#include <hip/hip_runtime.h>
#include <math.h>

// SchNet forward on MI355X.
// Core trick: the edge filter network ssp(rbf@w1+b1)@w2+b2 and the cosine
// cutoff depend only on scalar d (bounded by 5*sqrt(3) < 8.6603), so we
// tabulate W_total(d) on a 4096-point grid per interaction and lerp per edge.
// This removes ~94% of the FLOPs (219 GFLOP -> table builds of 1.1 GFLOP).

constexpr int Nn  = 50000;
constexpr int Ee  = 800000;
constexpr int Gg  = 512;
constexpr int Hh  = 128;
constexpr int Ff  = 128;
constexpr int NGg = 50;
constexpr int NIi = 6;
constexpr int TS  = 4096;           // table size
constexpr float DMAXv = 8.6603f;    // > 5*sqrt(3) = 8.660254

__device__ __forceinline__ float ssp(float v) {
    // softplus(v) - log(2), numerically stable
    return log1pf(__expf(-fabsf(v))) + fmaxf(v, 0.0f) - 0.69314718056f;
}

// ---------------- h = emb[z]  ----------------
__global__ void k_embed(const float* __restrict__ emb, const int* __restrict__ z,
                        float* __restrict__ h) {
    int tid = blockIdx.x * 256 + threadIdx.x;   // N*128 threads exactly
    int n = tid >> 7, f = tid & 127;
    h[tid] = emb[z[n] * Hh + f];
}

// ---------------- per-edge distance ----------------
__global__ void k_edgeprep(const float* __restrict__ pos, const int* __restrict__ ei,
                           float* __restrict__ d) {
    int e = blockIdx.x * 256 + threadIdx.x;
    if (e >= Ee) return;
    int r = ei[e], c = ei[Ee + e];
    float dx = pos[3 * r    ] - pos[3 * c    ];
    float dy = pos[3 * r + 1] - pos[3 * c + 1];
    float dz = pos[3 * r + 2] - pos[3 * c + 2];
    d[e] = sqrtf(dx * dx + dy * dy + dz * dz + 1e-12f);
}

// ---------------- filter table: T[j][f] = (ssp(rbf(dj)@w1+b1)@w2+b2)*C(dj) ----------------
__global__ void k_table(const float* __restrict__ w1, const float* __restrict__ b1,
                        const float* __restrict__ w2, const float* __restrict__ b2,
                        float* __restrict__ T, float step) {
    __shared__ float rbf[NGg];
    __shared__ float t[Ff];
    int j = blockIdx.x;
    int f = threadIdx.x;                 // 128 threads
    float dj = j * step;
    if (f < NGg) {
        float off = f * (10.0f / 49.0f);
        float u = dj - off;
        rbf[f] = expf(-12.00500f * u * u);    // coeff = -0.5/(10/49)^2
    }
    __syncthreads();
    float u = b1[f];
    for (int g = 0; g < NGg; ++g)
        u = fmaf(rbf[g], w1[g * Ff + f], u);
    t[f] = ssp(u);
    __syncthreads();
    float w = b2[f];
    for (int k = 0; k < Ff; ++k)
        w = fmaf(t[k], w2[k * Ff + f], w);
    float C = 0.5f * (cosf(dj * 0.31415926535f) + 1.0f);  // pi/CUTOFF = pi/10
    T[j * Ff + f] = w * C;
}

// ---------------- generic [N,128]@[128,128] GEMM (+bias, +ssp, +accumulate) ----------------
// 64 rows per block, in-tile staged in LDS (32KB), W streamed from global (L1/L2-hot).
// Thread (rq=tid>>5, fq=tid&31) computes rows rq*8..rq*8+7, cols fq*4..fq*4+3.
__global__ __launch_bounds__(256) void k_gemm128(
        const float* __restrict__ in, const float* __restrict__ W,
        const float* __restrict__ bias, int do_ssp, int do_acc,
        float* __restrict__ out, int nrows) {
    __shared__ float il[64 * 128];
    int tid = threadIdx.x;
    int base = blockIdx.x * 64;                 // first row of this block
    const float4* in4 = (const float4*)(in + (size_t)base * 128);
    float4* il4 = (float4*)il;
    int avail4 = (nrows * 128 - base * 128) >> 2;      // float4s available
    if (avail4 > 64 * 32) avail4 = 64 * 32;
    for (int i = tid; i < 64 * 32; i += 256)
        if (i < avail4) il4[i] = in4[i];
    __syncthreads();

    int rq = tid >> 5, fq = tid & 31;
    const float4* W4 = (const float4*)W;
    float4 acc[8];
    #pragma unroll
    for (int j = 0; j < 8; ++j) acc[j] = make_float4(0.f, 0.f, 0.f, 0.f);

    for (int k = 0; k < 128; ++k) {
        float4 w4 = W4[k * 32 + fq];
        #pragma unroll
        for (int j = 0; j < 8; ++j) {
            float a = il[(rq * 8 + j) * 128 + k];
            acc[j].x = fmaf(a, w4.x, acc[j].x);
            acc[j].y = fmaf(a, w4.y, acc[j].y);
            acc[j].z = fmaf(a, w4.z, acc[j].z);
            acc[j].w = fmaf(a, w4.w, acc[j].w);
        }
    }

    float4 bv = make_float4(0.f, 0.f, 0.f, 0.f);
    if (bias) bv = ((const float4*)bias)[fq];
    #pragma unroll
    for (int j = 0; j < 8; ++j) {
        int row = base + rq * 8 + j;
        if (row >= nrows) continue;
        float4 v = acc[j];
        v.x += bv.x; v.y += bv.y; v.z += bv.z; v.w += bv.w;
        if (do_ssp) { v.x = ssp(v.x); v.y = ssp(v.y); v.z = ssp(v.z); v.w = ssp(v.w); }
        float4* op = (float4*)(out + (size_t)row * 128 + fq * 4);
        if (do_acc) {
            float4 o = *op;
            o.x += v.x; o.y += v.y; o.z += v.z; o.w += v.w;
            *op = o;
        } else {
            *op = v;
        }
    }
}

// ---------------- edge gather/lerp/modulate/scatter ----------------
__global__ void k_edge(const float* __restrict__ d, const int* __restrict__ ei,
                       const float* __restrict__ x, const float* __restrict__ T,
                       float* __restrict__ agg, float inv_step, int total) {
    int stride = gridDim.x * 256;
    for (int idx = blockIdx.x * 256 + threadIdx.x; idx < total; idx += stride) {
        int e = idx >> 7;
        int f = idx & 127;
        float dv = d[e];
        float u = dv * inv_step;
        int j = (int)u;
        if (j > TS - 2) j = TS - 2;
        float fr = u - (float)j;
        float w = T[j * 128 + f] * (1.0f - fr) + T[(j + 1) * 128 + f] * fr;
        int row = ei[e];
        int col = ei[Ee + e];
        float msg = x[col * 128 + f] * w;
        unsafeAtomicAdd(&agg[row * 128 + f], msg);
    }
}

// ---------------- readout: per-atom MLP + segment-sum by batch ----------------
__global__ void k_out(const float* __restrict__ h, const float* __restrict__ ow1,
                      const float* __restrict__ ob1, const float* __restrict__ ow2,
                      const float* __restrict__ ob2, const int* __restrict__ batch,
                      float* __restrict__ energy) {
    int wid = threadIdx.x >> 6, lane = threadIdx.x & 63;
    int n = blockIdx.x * 4 + wid;
    if (n >= Nn) return;
    const float* hr = h + (size_t)n * 128;
    float acc = ob1[lane];
    for (int k = 0; k < 128; ++k)
        acc = fmaf(hr[k], ow1[k * 64 + lane], acc);
    float p = ssp(acc) * ow2[lane];
    #pragma unroll
    for (int off = 32; off > 0; off >>= 1) p += __shfl_down(p, off);
    if (lane == 0) unsafeAtomicAdd(&energy[batch[n]], p + ob2[0]);
}

extern "C" void kernel_launch(void* const* d_in, const int* in_sizes, int n_in,
                              void* d_out, int out_size, void* d_ws, size_t ws_size,
                              hipStream_t stream) {
    const float* pos    = (const float*)d_in[0];
    const float* emb    = (const float*)d_in[1];
    const float* w1     = (const float*)d_in[2];
    const float* b1     = (const float*)d_in[3];
    const float* w2     = (const float*)d_in[4];
    const float* b2     = (const float*)d_in[5];
    const float* lin1_w = (const float*)d_in[6];
    const float* lin2_w = (const float*)d_in[7];
    const float* lin2_b = (const float*)d_in[8];
    const float* lin_w  = (const float*)d_in[9];
    const float* lin_b  = (const float*)d_in[10];
    const float* ow1    = (const float*)d_in[11];
    const float* ob1    = (const float*)d_in[12];
    const float* ow2    = (const float*)d_in[13];
    const float* ob2    = (const float*)d_in[14];
    const int*   z      = (const int*)d_in[15];
    const int*   batch  = (const int*)d_in[16];
    const int*   ei     = (const int*)d_in[17];
    float* energy = (float*)d_out;

    char* ws = (char*)d_ws;
    float* h    = (float*)ws; ws += (size_t)Nn * 128 * 4;
    float* x    = (float*)ws; ws += (size_t)Nn * 128 * 4;
    float* agg  = (float*)ws; ws += (size_t)Nn * 128 * 4;
    float* dbuf = (float*)ws; ws += (size_t)Ee * 4;
    float* T    = (float*)ws; ws += (size_t)TS * 128 * 4;

    float step = DMAXv / (TS - 1);
    float inv_step = (TS - 1) / DMAXv;

    hipMemsetAsync(d_out, 0, Gg * 4, stream);
    k_embed<<<Nn * 128 / 256, 256, 0, stream>>>(emb, z, h);
    k_edgeprep<<<(Ee + 255) / 256, 256, 0, stream>>>(pos, ei, dbuf);

    int gemm_blocks = (Nn + 63) / 64;
    for (int i = 0; i < NIi; ++i) {
        k_table<<<TS, 128, 0, stream>>>(w1 + (size_t)i * NGg * Ff, b1 + (size_t)i * Ff,
                                        w2 + (size_t)i * Ff * Ff, b2 + (size_t)i * Ff,
                                        T, step);
        // x = h @ lin1_w[i]
        k_gemm128<<<gemm_blocks, 256, 0, stream>>>(h, lin1_w + (size_t)i * Hh * Ff,
                                                   nullptr, 0, 0, x, Nn);
        hipMemsetAsync(agg, 0, (size_t)Nn * 128 * 4, stream);
        k_edge<<<25600, 256, 0, stream>>>(dbuf, ei, x, T, agg, inv_step, Ee * 128);
        // x <- ssp(agg @ lin2_w[i] + lin2_b[i])   (reuse x buffer)
        k_gemm128<<<gemm_blocks, 256, 0, stream>>>(agg, lin2_w + (size_t)i * Ff * Hh,
                                                   lin2_b + (size_t)i * Hh, 1, 0, x, Nn);
        // h += x @ lin_w[i] + lin_b[i]
        k_gemm128<<<gemm_blocks, 256, 0, stream>>>(x, lin_w + (size_t)i * Hh * Hh,
                                                   lin_b + (size_t)i * Hh, 0, 1, h, Nn);
    }
    k_out<<<Nn / 4, 256, 0, stream>>>(h, ow1, ob1, ow2, ob2, batch, energy);
}

// Round 2
// 1681.100 us; speedup vs baseline: 1.8190x; 1.8190x over previous
//
#include <hip/hip_runtime.h>
#include <math.h>

// SchNet forward on MI355X.
// R1: edge filter W(d)*C(d) tabulated (4096-pt lerp) -> removed 94% of FLOPs.
// R2: atomics eliminated. On-device CSR sort (hist+scan+scatter), then
//     gather-only aggregation: 1 wave per node, float2 per lane, register acc.
//     Also fuse lin2+ssp+lin+residual into one LDS-reusing GEMM kernel.

constexpr int Nn  = 50000;
constexpr int Ee  = 800000;
constexpr int Gg  = 512;
constexpr int Hh  = 128;
constexpr int Ff  = 128;
constexpr int NGg = 50;
constexpr int NIi = 6;
constexpr int TS  = 4096;           // table size
constexpr float DMAXv = 8.6603f;    // > 5*sqrt(3) = 8.660254 (pos in [0,5)^3)

__device__ __forceinline__ float ssp(float v) {
    // softplus(v) - log(2), numerically stable
    return log1pf(__expf(-fabsf(v))) + fmaxf(v, 0.0f) - 0.69314718056f;
}

// ---------------- h = emb[z]  ----------------
__global__ void k_embed(const float* __restrict__ emb, const int* __restrict__ z,
                        float* __restrict__ h) {
    int tid = blockIdx.x * 256 + threadIdx.x;   // N*128 threads exactly
    int n = tid >> 7, f = tid & 127;
    h[tid] = emb[z[n] * Hh + f];
}

// ---------------- CSR build: histogram ----------------
__global__ void k_hist(const int* __restrict__ ei, int* __restrict__ counts) {
    int e = blockIdx.x * 256 + threadIdx.x;
    if (e >= Ee) return;
    atomicAdd(&counts[ei[e]], 1);
}

// ---------------- CSR build: exclusive scan (single block, 1024 thr) ----------------
__global__ __launch_bounds__(1024) void k_scan(const int* __restrict__ counts,
                                               int* __restrict__ offsets) {
    __shared__ int s[1024];
    constexpr int CH = (Nn + 1023) / 1024;   // 49
    int t = threadIdx.x;
    int beg = t * CH, end = beg + CH; if (end > Nn) end = Nn;
    int sum = 0;
    for (int i = beg; i < end; ++i) sum += counts[i];
    s[t] = sum;
    __syncthreads();
    for (int off = 1; off < 1024; off <<= 1) {
        int v = (t >= off) ? s[t - off] : 0;
        __syncthreads();
        s[t] += v;
        __syncthreads();
    }
    int base = (t == 0) ? 0 : s[t - 1];
    for (int i = beg; i < end; ++i) {
        offsets[i] = base;
        base += counts[i];
    }
    if (t == 1023) offsets[Nn] = base;
}

// ---------------- CSR build: scatter payload (col, u=d*inv_step) ----------------
__global__ void k_scatter(const int* __restrict__ ei, const float* __restrict__ pos,
                          int* __restrict__ cursor, int2* __restrict__ payload,
                          float inv_step) {
    int e = blockIdx.x * 256 + threadIdx.x;
    if (e >= Ee) return;
    int r = ei[e], c = ei[Ee + e];
    float dx = pos[3 * r    ] - pos[3 * c    ];
    float dy = pos[3 * r + 1] - pos[3 * c + 1];
    float dz = pos[3 * r + 2] - pos[3 * c + 2];
    float d = sqrtf(dx * dx + dy * dy + dz * dz + 1e-12f);
    float u = d * inv_step;
    if (u > (float)(TS - 1) - 5e-4f) u = (float)(TS - 1) - 5e-4f;
    int p = atomicAdd(&cursor[r], 1);
    payload[p] = make_int2(c, __float_as_int(u));
}

// ---------------- filter table: T[j][f] = (ssp(rbf(dj)@w1+b1)@w2+b2)*C(dj) ----------------
__global__ void k_table(const float* __restrict__ w1, const float* __restrict__ b1,
                        const float* __restrict__ w2, const float* __restrict__ b2,
                        float* __restrict__ T, float step) {
    __shared__ float rbf[NGg];
    __shared__ float t[Ff];
    int j = blockIdx.x;
    int f = threadIdx.x;                 // 128 threads
    float dj = j * step;
    if (f < NGg) {
        float off = f * (10.0f / 49.0f);
        float u = dj - off;
        rbf[f] = expf(-12.00500f * u * u);    // coeff = -0.5/(10/49)^2
    }
    __syncthreads();
    float u = b1[f];
    for (int g = 0; g < NGg; ++g)
        u = fmaf(rbf[g], w1[g * Ff + f], u);
    t[f] = ssp(u);
    __syncthreads();
    float w = b2[f];
    for (int k = 0; k < Ff; ++k)
        w = fmaf(t[k], w2[k * Ff + f], w);
    float C = 0.5f * (cosf(dj * 0.31415926535f) + 1.0f);  // pi/CUTOFF = pi/10
    T[j * Ff + f] = w * C;
}

// ---------------- x = in @ W (no bias/act), [N,128]@[128,128] ----------------
__global__ __launch_bounds__(256) void k_gemm128(
        const float* __restrict__ in, const float* __restrict__ W,
        float* __restrict__ out, int nrows) {
    __shared__ float il[64 * 128];
    int tid = threadIdx.x;
    int base = blockIdx.x * 64;
    const float4* in4 = (const float4*)(in + (size_t)base * 128);
    float4* il4 = (float4*)il;
    int avail4 = (nrows * 128 - base * 128) >> 2;
    if (avail4 > 64 * 32) avail4 = 64 * 32;
    for (int i = tid; i < 64 * 32; i += 256)
        if (i < avail4) il4[i] = in4[i];
    __syncthreads();

    int rq = tid >> 5, fq = tid & 31;
    const float4* W4 = (const float4*)W;
    float4 acc[8];
    #pragma unroll
    for (int j = 0; j < 8; ++j) acc[j] = make_float4(0.f, 0.f, 0.f, 0.f);
    for (int k = 0; k < 128; ++k) {
        float4 w4 = W4[k * 32 + fq];
        #pragma unroll
        for (int j = 0; j < 8; ++j) {
            float a = il[(rq * 8 + j) * 128 + k];
            acc[j].x = fmaf(a, w4.x, acc[j].x);
            acc[j].y = fmaf(a, w4.y, acc[j].y);
            acc[j].z = fmaf(a, w4.z, acc[j].z);
            acc[j].w = fmaf(a, w4.w, acc[j].w);
        }
    }
    #pragma unroll
    for (int j = 0; j < 8; ++j) {
        int row = base + rq * 8 + j;
        if (row >= nrows) continue;
        ((float4*)(out + (size_t)row * 128 + fq * 4))[0] = acc[j];
    }
}

// ---------------- fused: h += ssp(agg@lin2+b2) @ lin3 + b3 ----------------
// Reuses the 32KB LDS tile: stage agg -> compute t=ssp(.) -> write t back
// into the same tile -> second GEMM -> accumulate into h.
__global__ __launch_bounds__(256) void k_gemm23(
        const float* __restrict__ agg, const float* __restrict__ W2,
        const float* __restrict__ b2, const float* __restrict__ W3,
        const float* __restrict__ b3, float* __restrict__ h, int nrows) {
    __shared__ float il[64 * 128];
    int tid = threadIdx.x;
    int base = blockIdx.x * 64;
    const float4* in4 = (const float4*)(agg + (size_t)base * 128);
    float4* il4 = (float4*)il;
    int avail4 = (nrows * 128 - base * 128) >> 2;
    if (avail4 > 64 * 32) avail4 = 64 * 32;
    for (int i = tid; i < 64 * 32; i += 256)
        if (i < avail4) il4[i] = in4[i];
    __syncthreads();

    int rq = tid >> 5, fq = tid & 31;
    float4 acc[8];
    #pragma unroll
    for (int j = 0; j < 8; ++j) acc[j] = make_float4(0.f, 0.f, 0.f, 0.f);
    const float4* W24 = (const float4*)W2;
    for (int k = 0; k < 128; ++k) {
        float4 w4 = W24[k * 32 + fq];
        #pragma unroll
        for (int j = 0; j < 8; ++j) {
            float a = il[(rq * 8 + j) * 128 + k];
            acc[j].x = fmaf(a, w4.x, acc[j].x);
            acc[j].y = fmaf(a, w4.y, acc[j].y);
            acc[j].z = fmaf(a, w4.z, acc[j].z);
            acc[j].w = fmaf(a, w4.w, acc[j].w);
        }
    }
    float4 bv = ((const float4*)b2)[fq];
    __syncthreads();                     // all reads of il done
    #pragma unroll
    for (int j = 0; j < 8; ++j) {
        float4 v = acc[j];
        v.x = ssp(v.x + bv.x); v.y = ssp(v.y + bv.y);
        v.z = ssp(v.z + bv.z); v.w = ssp(v.w + bv.w);
        ((float4*)(il + (rq * 8 + j) * 128 + fq * 4))[0] = v;
        acc[j] = make_float4(0.f, 0.f, 0.f, 0.f);
    }
    __syncthreads();
    const float4* W34 = (const float4*)W3;
    for (int k = 0; k < 128; ++k) {
        float4 w4 = W34[k * 32 + fq];
        #pragma unroll
        for (int j = 0; j < 8; ++j) {
            float a = il[(rq * 8 + j) * 128 + k];
            acc[j].x = fmaf(a, w4.x, acc[j].x);
            acc[j].y = fmaf(a, w4.y, acc[j].y);
            acc[j].z = fmaf(a, w4.z, acc[j].z);
            acc[j].w = fmaf(a, w4.w, acc[j].w);
        }
    }
    float4 b3v = ((const float4*)b3)[fq];
    #pragma unroll
    for (int j = 0; j < 8; ++j) {
        int row = base + rq * 8 + j;
        if (row >= nrows) continue;
        float4* op = (float4*)(h + (size_t)row * 128 + fq * 4);
        float4 o = *op;
        o.x += acc[j].x + b3v.x; o.y += acc[j].y + b3v.y;
        o.z += acc[j].z + b3v.z; o.w += acc[j].w + b3v.w;
        *op = o;
    }
}

// ---------------- aggregation: 1 wave per node, gather + lerp + reg-accumulate ----------------
__global__ __launch_bounds__(256) void k_agg(
        const int* __restrict__ offs, const int2* __restrict__ payload,
        const float* __restrict__ x, const float* __restrict__ T,
        float* __restrict__ agg) {
    int wid = threadIdx.x >> 6, lane = threadIdx.x & 63;
    int n = blockIdx.x * 4 + wid;
    int beg = offs[n], end = offs[n + 1];
    const float2* T2 = (const float2*)T + lane;
    const float2* X2 = (const float2*)x + lane;
    float2 acc = make_float2(0.f, 0.f);
    if (beg < end) {
        int2 pl = payload[beg];
        for (int e = beg; e < end; ++e) {
            int2 cur = pl;
            if (e + 1 < end) pl = payload[e + 1];       // prefetch next
            int col = cur.x;
            float u = __int_as_float(cur.y);
            int j = (int)u;
            float fr = u - (float)j;
            float2 t0 = T2[j * 64];
            float2 t1 = T2[j * 64 + 64];
            float2 xv = X2[col * 64];
            acc.x = fmaf(xv.x, fmaf(t1.x - t0.x, fr, t0.x), acc.x);
            acc.y = fmaf(xv.y, fmaf(t1.y - t0.y, fr, t0.y), acc.y);
        }
    }
    ((float2*)agg)[n * 64 + lane] = acc;
}

// ---------------- readout: per-atom MLP + segment-sum by batch ----------------
__global__ void k_out(const float* __restrict__ h, const float* __restrict__ ow1,
                      const float* __restrict__ ob1, const float* __restrict__ ow2,
                      const float* __restrict__ ob2, const int* __restrict__ batch,
                      float* __restrict__ energy) {
    int wid = threadIdx.x >> 6, lane = threadIdx.x & 63;
    int n = blockIdx.x * 4 + wid;
    if (n >= Nn) return;
    const float* hr = h + (size_t)n * 128;
    float acc = ob1[lane];
    for (int k = 0; k < 128; ++k)
        acc = fmaf(hr[k], ow1[k * 64 + lane], acc);
    float p = ssp(acc) * ow2[lane];
    #pragma unroll
    for (int off = 32; off > 0; off >>= 1) p += __shfl_down(p, off);
    if (lane == 0) unsafeAtomicAdd(&energy[batch[n]], p + ob2[0]);
}

extern "C" void kernel_launch(void* const* d_in, const int* in_sizes, int n_in,
                              void* d_out, int out_size, void* d_ws, size_t ws_size,
                              hipStream_t stream) {
    const float* pos    = (const float*)d_in[0];
    const float* emb    = (const float*)d_in[1];
    const float* w1     = (const float*)d_in[2];
    const float* b1     = (const float*)d_in[3];
    const float* w2     = (const float*)d_in[4];
    const float* b2     = (const float*)d_in[5];
    const float* lin1_w = (const float*)d_in[6];
    const float* lin2_w = (const float*)d_in[7];
    const float* lin2_b = (const float*)d_in[8];
    const float* lin_w  = (const float*)d_in[9];
    const float* lin_b  = (const float*)d_in[10];
    const float* ow1    = (const float*)d_in[11];
    const float* ob1    = (const float*)d_in[12];
    const float* ow2    = (const float*)d_in[13];
    const float* ob2    = (const float*)d_in[14];
    const int*   z      = (const int*)d_in[15];
    const int*   batch  = (const int*)d_in[16];
    const int*   ei     = (const int*)d_in[17];
    float* energy = (float*)d_out;

    char* ws = (char*)d_ws;
    float* h       = (float*)ws; ws += (size_t)Nn * 128 * 4;
    float* x       = (float*)ws; ws += (size_t)Nn * 128 * 4;
    float* agg     = (float*)ws; ws += (size_t)Nn * 128 * 4;
    float* T       = (float*)ws; ws += (size_t)TS * 128 * 4;
    int2*  payload = (int2*)ws;  ws += (size_t)Ee * 8;
    int*   counts  = (int*)ws;   ws += (size_t)Nn * 4;
    int*   offsets = (int*)ws;   ws += (size_t)(Nn + 1) * 4;
    int*   cursor  = (int*)ws;   ws += (size_t)Nn * 4;

    float step = DMAXv / (TS - 1);
    float inv_step = (TS - 1) / DMAXv;

    hipMemsetAsync(d_out, 0, Gg * 4, stream);
    hipMemsetAsync(counts, 0, (size_t)Nn * 4, stream);
    k_embed<<<Nn * 128 / 256, 256, 0, stream>>>(emb, z, h);

    // CSR sort of edges by target row
    k_hist<<<(Ee + 255) / 256, 256, 0, stream>>>(ei, counts);
    k_scan<<<1, 1024, 0, stream>>>(counts, offsets);
    hipMemcpyAsync(cursor, offsets, (size_t)Nn * 4, hipMemcpyDeviceToDevice, stream);
    k_scatter<<<(Ee + 255) / 256, 256, 0, stream>>>(ei, pos, cursor, payload, inv_step);

    int gemm_blocks = (Nn + 63) / 64;
    for (int i = 0; i < NIi; ++i) {
        k_table<<<TS, 128, 0, stream>>>(w1 + (size_t)i * NGg * Ff, b1 + (size_t)i * Ff,
                                        w2 + (size_t)i * Ff * Ff, b2 + (size_t)i * Ff,
                                        T, step);
        k_gemm128<<<gemm_blocks, 256, 0, stream>>>(h, lin1_w + (size_t)i * Hh * Ff, x, Nn);
        k_agg<<<Nn / 4, 256, 0, stream>>>(offsets, payload, x, T, agg);
        k_gemm23<<<gemm_blocks, 256, 0, stream>>>(agg, lin2_w + (size_t)i * Ff * Hh,
                                                  lin2_b + (size_t)i * Hh,
                                                  lin_w + (size_t)i * Hh * Hh,
                                                  lin_b + (size_t)i * Hh, h, Nn);
    }
    k_out<<<Nn / 4, 256, 0, stream>>>(h, ow1, ob1, ow2, ob2, batch, energy);
}

// Round 5
// 1418.984 us; speedup vs baseline: 2.1550x; 1.1847x over previous
//
#include <hip/hip_runtime.h>
#include <math.h>

// SchNet forward on MI355X.
// R1: edge filter W(d)*C(d) tabulated (4096-pt lerp) -> removed 94% of FLOPs.
// R2: CSR sort (hist+scan+scatter) -> gather-only aggregation, no atomics.
// R3: k_out restructured GEMM-style (was 158us latency-bound); x and T in
//     bf16 (halves k_agg gather traffic; accumulation stays fp32);
//     float4 LDS reads in all GEMMs; k_table stages w1/w2 in LDS.
// R4/R5: resubmit of R3 (bench infra timeouts, no results).

constexpr int Nn  = 50000;
constexpr int Ee  = 800000;
constexpr int Gg  = 512;
constexpr int Hh  = 128;
constexpr int NGg = 50;
constexpr int NIi = 6;
constexpr int TS  = 4096;           // table size
constexpr float DMAXv = 8.6603f;    // > 5*sqrt(3) = 8.660254 (pos in [0,5)^3)

__device__ __forceinline__ float ssp(float v) {
    // softplus(v) - log(2), numerically stable
    return log1pf(__expf(-fabsf(v))) + fmaxf(v, 0.0f) - 0.69314718056f;
}
__device__ __forceinline__ unsigned short f2bf(float f) {   // RNE
    unsigned int u = __float_as_uint(f);
    u += 0x7fffu + ((u >> 16) & 1u);
    return (unsigned short)(u >> 16);
}
__device__ __forceinline__ float bf2f(unsigned int h) {     // h: low 16 bits
    return __uint_as_float(h << 16);
}

// ---------------- h = emb[z]  ----------------
__global__ void k_embed(const float* __restrict__ emb, const int* __restrict__ z,
                        float* __restrict__ h) {
    int tid = blockIdx.x * 256 + threadIdx.x;   // N*128 threads exactly
    int n = tid >> 7, f = tid & 127;
    h[tid] = emb[z[n] * Hh + f];
}

// ---------------- CSR build ----------------
__global__ void k_hist(const int* __restrict__ ei, int* __restrict__ counts) {
    int e = blockIdx.x * 256 + threadIdx.x;
    if (e >= Ee) return;
    atomicAdd(&counts[ei[e]], 1);
}

__global__ __launch_bounds__(1024) void k_scan(const int* __restrict__ counts,
                                               int* __restrict__ offsets) {
    __shared__ int s[1024];
    constexpr int CH = (Nn + 1023) / 1024;
    int t = threadIdx.x;
    int beg = t * CH, end = beg + CH; if (end > Nn) end = Nn;
    int sum = 0;
    for (int i = beg; i < end; ++i) sum += counts[i];
    s[t] = sum;
    __syncthreads();
    for (int off = 1; off < 1024; off <<= 1) {
        int v = (t >= off) ? s[t - off] : 0;
        __syncthreads();
        s[t] += v;
        __syncthreads();
    }
    int base = (t == 0) ? 0 : s[t - 1];
    for (int i = beg; i < end; ++i) {
        offsets[i] = base;
        base += counts[i];
    }
    if (t == 1023) offsets[Nn] = base;
}

__global__ void k_scatter(const int* __restrict__ ei, const float* __restrict__ pos,
                          int* __restrict__ cursor, int2* __restrict__ payload,
                          float inv_step) {
    int e = blockIdx.x * 256 + threadIdx.x;
    if (e >= Ee) return;
    int r = ei[e], c = ei[Ee + e];
    float dx = pos[3 * r    ] - pos[3 * c    ];
    float dy = pos[3 * r + 1] - pos[3 * c + 1];
    float dz = pos[3 * r + 2] - pos[3 * c + 2];
    float d = sqrtf(dx * dx + dy * dy + dz * dz + 1e-12f);
    float u = d * inv_step;
    if (u > (float)(TS - 1) - 5e-4f) u = (float)(TS - 1) - 5e-4f;
    int p = atomicAdd(&cursor[r], 1);
    payload[p] = make_int2(c, __float_as_int(u));
}

// ---------------- filter table (bf16 out): 256 blocks x 16 j each ----------------
__global__ __launch_bounds__(256) void k_table(
        const float* __restrict__ w1, const float* __restrict__ b1,
        const float* __restrict__ w2, const float* __restrict__ b2,
        unsigned short* __restrict__ T, float step) {
    __shared__ float w2s[128 * 128];      // 64 KB
    __shared__ float w1s[NGg * 128];      // 25.6 KB
    __shared__ float rbf_s[2][NGg];
    __shared__ float tb[2][128];
    int tid = threadIdx.x;
    for (int i = tid; i < 128 * 128; i += 256) w2s[i] = w2[i];
    for (int i = tid; i < NGg * 128; i += 256) w1s[i] = w1[i];
    int jj = tid >> 7, f = tid & 127;
    float bb1 = b1[f], bb2 = b2[f];
    for (int p = 0; p < 8; ++p) {
        int j = blockIdx.x * 16 + p * 2 + jj;
        float dj = j * step;
        __syncthreads();                 // staging done / prev iter reads done
        if (f < NGg) {
            float u = dj - f * (10.0f / 49.0f);
            rbf_s[jj][f] = expf(-12.00500f * u * u);   // -0.5/(10/49)^2
        }
        __syncthreads();
        float u = bb1;
        for (int g = 0; g < NGg; ++g)
            u = fmaf(rbf_s[jj][g], w1s[g * 128 + f], u);
        tb[jj][f] = ssp(u);
        __syncthreads();
        float w = bb2;
        for (int k = 0; k < 128; ++k)
            w = fmaf(tb[jj][k], w2s[k * 128 + f], w);
        float C = 0.5f * (cosf(dj * 0.31415926535f) + 1.0f);  // pi/10
        T[j * 128 + f] = f2bf(w * C);
    }
}

// ---------------- x(bf16) = h @ lin1 ----------------
__global__ __launch_bounds__(256) void k_gemm1(
        const float* __restrict__ in, const float* __restrict__ W,
        unsigned short* __restrict__ out, int nrows) {
    __shared__ float il[64 * 128];
    int tid = threadIdx.x;
    int base = blockIdx.x * 64;
    const float4* in4 = (const float4*)(in + (size_t)base * 128);
    float4* il4 = (float4*)il;
    int avail4 = (nrows - base) * 32; if (avail4 > 2048) avail4 = 2048;
    for (int i = tid; i < 2048; i += 256)
        if (i < avail4) il4[i] = in4[i];
    __syncthreads();

    int rq = tid >> 5, fq = tid & 31;
    const float4* W4 = (const float4*)W;
    float4 acc[8];
    #pragma unroll
    for (int j = 0; j < 8; ++j) acc[j] = make_float4(0.f, 0.f, 0.f, 0.f);
    for (int kk = 0; kk < 32; ++kk) {
        float4 wa = W4[(kk * 4 + 0) * 32 + fq];
        float4 wb = W4[(kk * 4 + 1) * 32 + fq];
        float4 wc = W4[(kk * 4 + 2) * 32 + fq];
        float4 wd = W4[(kk * 4 + 3) * 32 + fq];
        #pragma unroll
        for (int j = 0; j < 8; ++j) {
            float4 a = il4[(rq * 8 + j) * 32 + kk];
            acc[j].x = fmaf(a.x, wa.x, acc[j].x); acc[j].y = fmaf(a.x, wa.y, acc[j].y);
            acc[j].z = fmaf(a.x, wa.z, acc[j].z); acc[j].w = fmaf(a.x, wa.w, acc[j].w);
            acc[j].x = fmaf(a.y, wb.x, acc[j].x); acc[j].y = fmaf(a.y, wb.y, acc[j].y);
            acc[j].z = fmaf(a.y, wb.z, acc[j].z); acc[j].w = fmaf(a.y, wb.w, acc[j].w);
            acc[j].x = fmaf(a.z, wc.x, acc[j].x); acc[j].y = fmaf(a.z, wc.y, acc[j].y);
            acc[j].z = fmaf(a.z, wc.z, acc[j].z); acc[j].w = fmaf(a.z, wc.w, acc[j].w);
            acc[j].x = fmaf(a.w, wd.x, acc[j].x); acc[j].y = fmaf(a.w, wd.y, acc[j].y);
            acc[j].z = fmaf(a.w, wd.z, acc[j].z); acc[j].w = fmaf(a.w, wd.w, acc[j].w);
        }
    }
    #pragma unroll
    for (int j = 0; j < 8; ++j) {
        int row = base + rq * 8 + j;
        if (row >= nrows) continue;
        ushort4 o;
        o.x = f2bf(acc[j].x); o.y = f2bf(acc[j].y);
        o.z = f2bf(acc[j].z); o.w = f2bf(acc[j].w);
        ((ushort4*)(out + (size_t)row * 128 + fq * 4))[0] = o;
    }
}

// ---------------- fused: h += ssp(agg@lin2+b2) @ lin3 + b3 ----------------
__global__ __launch_bounds__(256) void k_gemm23(
        const float* __restrict__ agg, const float* __restrict__ W2,
        const float* __restrict__ b2, const float* __restrict__ W3,
        const float* __restrict__ b3, float* __restrict__ h, int nrows) {
    __shared__ float il[64 * 128];
    int tid = threadIdx.x;
    int base = blockIdx.x * 64;
    const float4* in4 = (const float4*)(agg + (size_t)base * 128);
    float4* il4 = (float4*)il;
    int avail4 = (nrows - base) * 32; if (avail4 > 2048) avail4 = 2048;
    for (int i = tid; i < 2048; i += 256)
        if (i < avail4) il4[i] = in4[i];
    __syncthreads();

    int rq = tid >> 5, fq = tid & 31;
    float4 acc[8];
    #pragma unroll
    for (int j = 0; j < 8; ++j) acc[j] = make_float4(0.f, 0.f, 0.f, 0.f);
    const float4* W24 = (const float4*)W2;
    for (int kk = 0; kk < 32; ++kk) {
        float4 wa = W24[(kk * 4 + 0) * 32 + fq];
        float4 wb = W24[(kk * 4 + 1) * 32 + fq];
        float4 wc = W24[(kk * 4 + 2) * 32 + fq];
        float4 wd = W24[(kk * 4 + 3) * 32 + fq];
        #pragma unroll
        for (int j = 0; j < 8; ++j) {
            float4 a = il4[(rq * 8 + j) * 32 + kk];
            acc[j].x = fmaf(a.x, wa.x, acc[j].x); acc[j].y = fmaf(a.x, wa.y, acc[j].y);
            acc[j].z = fmaf(a.x, wa.z, acc[j].z); acc[j].w = fmaf(a.x, wa.w, acc[j].w);
            acc[j].x = fmaf(a.y, wb.x, acc[j].x); acc[j].y = fmaf(a.y, wb.y, acc[j].y);
            acc[j].z = fmaf(a.y, wb.z, acc[j].z); acc[j].w = fmaf(a.y, wb.w, acc[j].w);
            acc[j].x = fmaf(a.z, wc.x, acc[j].x); acc[j].y = fmaf(a.z, wc.y, acc[j].y);
            acc[j].z = fmaf(a.z, wc.z, acc[j].z); acc[j].w = fmaf(a.z, wc.w, acc[j].w);
            acc[j].x = fmaf(a.w, wd.x, acc[j].x); acc[j].y = fmaf(a.w, wd.y, acc[j].y);
            acc[j].z = fmaf(a.w, wd.z, acc[j].z); acc[j].w = fmaf(a.w, wd.w, acc[j].w);
        }
    }
    float4 bv = ((const float4*)b2)[fq];
    __syncthreads();                     // all reads of il done
    #pragma unroll
    for (int j = 0; j < 8; ++j) {
        float4 v = acc[j];
        v.x = ssp(v.x + bv.x); v.y = ssp(v.y + bv.y);
        v.z = ssp(v.z + bv.z); v.w = ssp(v.w + bv.w);
        il4[(rq * 8 + j) * 32 + fq] = v;
        acc[j] = make_float4(0.f, 0.f, 0.f, 0.f);
    }
    __syncthreads();
    const float4* W34 = (const float4*)W3;
    for (int kk = 0; kk < 32; ++kk) {
        float4 wa = W34[(kk * 4 + 0) * 32 + fq];
        float4 wb = W34[(kk * 4 + 1) * 32 + fq];
        float4 wc = W34[(kk * 4 + 2) * 32 + fq];
        float4 wd = W34[(kk * 4 + 3) * 32 + fq];
        #pragma unroll
        for (int j = 0; j < 8; ++j) {
            float4 a = il4[(rq * 8 + j) * 32 + kk];
            acc[j].x = fmaf(a.x, wa.x, acc[j].x); acc[j].y = fmaf(a.x, wa.y, acc[j].y);
            acc[j].z = fmaf(a.x, wa.z, acc[j].z); acc[j].w = fmaf(a.x, wa.w, acc[j].w);
            acc[j].x = fmaf(a.y, wb.x, acc[j].x); acc[j].y = fmaf(a.y, wb.y, acc[j].y);
            acc[j].z = fmaf(a.y, wb.z, acc[j].z); acc[j].w = fmaf(a.y, wb.w, acc[j].w);
            acc[j].x = fmaf(a.z, wc.x, acc[j].x); acc[j].y = fmaf(a.z, wc.y, acc[j].y);
            acc[j].z = fmaf(a.z, wc.z, acc[j].z); acc[j].w = fmaf(a.z, wc.w, acc[j].w);
            acc[j].x = fmaf(a.w, wd.x, acc[j].x); acc[j].y = fmaf(a.w, wd.y, acc[j].y);
            acc[j].z = fmaf(a.w, wd.z, acc[j].z); acc[j].w = fmaf(a.w, wd.w, acc[j].w);
        }
    }
    float4 b3v = ((const float4*)b3)[fq];
    #pragma unroll
    for (int j = 0; j < 8; ++j) {
        int row = base + rq * 8 + j;
        if (row >= nrows) continue;
        float4* op = (float4*)(h + (size_t)row * 128 + fq * 4);
        float4 o = *op;
        o.x += acc[j].x + b3v.x; o.y += acc[j].y + b3v.y;
        o.z += acc[j].z + b3v.z; o.w += acc[j].w + b3v.w;
        *op = o;
    }
}

// ---------------- aggregation: 1 wave/node, bf16 gather + lerp, fp32 acc ----------------
__global__ __launch_bounds__(256) void k_agg(
        const int* __restrict__ offs, const int2* __restrict__ payload,
        const unsigned int* __restrict__ xw, const unsigned int* __restrict__ Tw,
        float* __restrict__ agg) {
    int wid = threadIdx.x >> 6, lane = threadIdx.x & 63;
    int n = blockIdx.x * 4 + wid;
    int beg = offs[n], end = offs[n + 1];
    float2 acc = make_float2(0.f, 0.f);
    if (beg < end) {
        int2 pl = payload[beg];
        for (int e = beg; e < end; ++e) {
            int2 cur = pl;
            if (e + 1 < end) pl = payload[e + 1];   // prefetch
            int col = cur.x;
            float u = __int_as_float(cur.y);
            int j = (int)u;
            float fr = u - (float)j;
            unsigned int t0 = Tw[j * 64 + lane];
            unsigned int t1 = Tw[j * 64 + 64 + lane];
            unsigned int xv = xw[(size_t)col * 64 + lane];
            float t0a = bf2f(t0 & 0xffffu), t0b = bf2f(t0 >> 16);
            float t1a = bf2f(t1 & 0xffffu), t1b = bf2f(t1 >> 16);
            float xa  = bf2f(xv & 0xffffu), xb  = bf2f(xv >> 16);
            acc.x = fmaf(xa, fmaf(t1a - t0a, fr, t0a), acc.x);
            acc.y = fmaf(xb, fmaf(t1b - t0b, fr, t0b), acc.y);
        }
    }
    ((float2*)agg)[(size_t)n * 64 + lane] = acc;
}

// ---------------- readout: GEMM-style per-atom MLP + segment sum ----------------
__global__ __launch_bounds__(256) void k_out(
        const float* __restrict__ h, const float* __restrict__ ow1,
        const float* __restrict__ ob1, const float* __restrict__ ow2,
        const float* __restrict__ ob2, const int* __restrict__ batch,
        float* __restrict__ energy, int nrows) {
    __shared__ float il[64 * 128];
    __shared__ float red[64 * 33];       // padded: conflict-free column reads
    int tid = threadIdx.x;
    int base = blockIdx.x * 64;
    const float4* in4 = (const float4*)(h + (size_t)base * 128);
    float4* il4 = (float4*)il;
    int avail4 = (nrows - base) * 32; if (avail4 > 2048) avail4 = 2048;
    for (int i = tid; i < 2048; i += 256)
        if (i < avail4) il4[i] = in4[i];
    __syncthreads();

    int rq = tid >> 5, fq = tid & 31;
    float2 acc[8];
    #pragma unroll
    for (int j = 0; j < 8; ++j) acc[j] = make_float2(0.f, 0.f);
    const float2* W2 = (const float2*)ow1;     // [128][32] float2
    for (int kk = 0; kk < 32; ++kk) {
        float2 wa = W2[(kk * 4 + 0) * 32 + fq];
        float2 wb = W2[(kk * 4 + 1) * 32 + fq];
        float2 wc = W2[(kk * 4 + 2) * 32 + fq];
        float2 wd = W2[(kk * 4 + 3) * 32 + fq];
        #pragma unroll
        for (int j = 0; j < 8; ++j) {
            float4 a = il4[(rq * 8 + j) * 32 + kk];
            acc[j].x = fmaf(a.x, wa.x, acc[j].x); acc[j].y = fmaf(a.x, wa.y, acc[j].y);
            acc[j].x = fmaf(a.y, wb.x, acc[j].x); acc[j].y = fmaf(a.y, wb.y, acc[j].y);
            acc[j].x = fmaf(a.z, wc.x, acc[j].x); acc[j].y = fmaf(a.z, wc.y, acc[j].y);
            acc[j].x = fmaf(a.w, wd.x, acc[j].x); acc[j].y = fmaf(a.w, wd.y, acc[j].y);
        }
    }
    float2 b1v = ((const float2*)ob1)[fq];
    float2 w2v = ((const float2*)ow2)[fq];
    #pragma unroll
    for (int j = 0; j < 8; ++j) {
        float pa = ssp(acc[j].x + b1v.x) * w2v.x + ssp(acc[j].y + b1v.y) * w2v.y;
        red[(rq * 8 + j) * 33 + fq] = pa;
    }
    __syncthreads();
    if (tid < 64) {
        int row = base + tid;
        if (row < nrows) {
            float s = 0.f;
            #pragma unroll
            for (int i = 0; i < 32; ++i) s += red[tid * 33 + i];
            unsafeAtomicAdd(&energy[batch[row]], s + ob2[0]);
        }
    }
}

extern "C" void kernel_launch(void* const* d_in, const int* in_sizes, int n_in,
                              void* d_out, int out_size, void* d_ws, size_t ws_size,
                              hipStream_t stream) {
    const float* pos    = (const float*)d_in[0];
    const float* emb    = (const float*)d_in[1];
    const float* w1     = (const float*)d_in[2];
    const float* b1     = (const float*)d_in[3];
    const float* w2     = (const float*)d_in[4];
    const float* b2     = (const float*)d_in[5];
    const float* lin1_w = (const float*)d_in[6];
    const float* lin2_w = (const float*)d_in[7];
    const float* lin2_b = (const float*)d_in[8];
    const float* lin_w  = (const float*)d_in[9];
    const float* lin_b  = (const float*)d_in[10];
    const float* ow1    = (const float*)d_in[11];
    const float* ob1    = (const float*)d_in[12];
    const float* ow2    = (const float*)d_in[13];
    const float* ob2    = (const float*)d_in[14];
    const int*   z      = (const int*)d_in[15];
    const int*   batch  = (const int*)d_in[16];
    const int*   ei     = (const int*)d_in[17];
    float* energy = (float*)d_out;

    char* ws = (char*)d_ws;
    float*          h       = (float*)ws;          ws += (size_t)Nn * 128 * 4;
    float*          agg     = (float*)ws;          ws += (size_t)Nn * 128 * 4;
    unsigned short* xb      = (unsigned short*)ws; ws += (size_t)Nn * 128 * 2;
    unsigned short* T       = (unsigned short*)ws; ws += (size_t)TS * 128 * 2;
    int2*           payload = (int2*)ws;           ws += (size_t)Ee * 8;
    int*            counts  = (int*)ws;            ws += (size_t)Nn * 4;
    int*            offsets = (int*)ws;            ws += (size_t)(Nn + 1) * 4;
    int*            cursor  = (int*)ws;            ws += (size_t)Nn * 4;

    float step = DMAXv / (TS - 1);
    float inv_step = (TS - 1) / DMAXv;

    hipMemsetAsync(d_out, 0, Gg * 4, stream);
    hipMemsetAsync(counts, 0, (size_t)Nn * 4, stream);
    k_embed<<<Nn * 128 / 256, 256, 0, stream>>>(emb, z, h);

    // CSR sort of edges by target row
    k_hist<<<(Ee + 255) / 256, 256, 0, stream>>>(ei, counts);
    k_scan<<<1, 1024, 0, stream>>>(counts, offsets);
    hipMemcpyAsync(cursor, offsets, (size_t)Nn * 4, hipMemcpyDeviceToDevice, stream);
    k_scatter<<<(Ee + 255) / 256, 256, 0, stream>>>(ei, pos, cursor, payload, inv_step);

    int gemm_blocks = (Nn + 63) / 64;
    for (int i = 0; i < NIi; ++i) {
        k_table<<<256, 256, 0, stream>>>(w1 + (size_t)i * NGg * 128, b1 + (size_t)i * 128,
                                         w2 + (size_t)i * 128 * 128, b2 + (size_t)i * 128,
                                         T, step);
        k_gemm1<<<gemm_blocks, 256, 0, stream>>>(h, lin1_w + (size_t)i * Hh * 128, xb, Nn);
        k_agg<<<Nn / 4, 256, 0, stream>>>(offsets, payload,
                                          (const unsigned int*)xb, (const unsigned int*)T, agg);
        k_gemm23<<<gemm_blocks, 256, 0, stream>>>(agg, lin2_w + (size_t)i * 128 * Hh,
                                                  lin2_b + (size_t)i * Hh,
                                                  lin_w + (size_t)i * Hh * Hh,
                                                  lin_b + (size_t)i * Hh, h, Nn);
    }
    k_out<<<gemm_blocks, 256, 0, stream>>>(h, ow1, ob1, ow2, ob2, batch, energy, Nn);
}

// Round 6
// 1201.350 us; speedup vs baseline: 2.5455x; 1.1812x over previous
//
#include <hip/hip_runtime.h>
#include <math.h>

// SchNet forward on MI355X.
// R1: edge filter W(d)*C(d) tabulated (4096-pt lerp) -> removed 94% of FLOPs.
// R2: CSR sort (hist+scan+scatter) -> gather-only aggregation, no atomics.
// R3: k_out GEMM-style; x,T bf16; k_table stages weights in LDS.
// R6: node GEMMs -> MFMA bf16 (16x16x32), weights pre-packed to fragment
//     layout (L1-resident 16B/lane loads); A-tiles in XOR-swizzled LDS;
//     k_out stages ow1 in LDS (was streaming global in inner loop ->
//     latency-bound at 12% occupancy, 91us).

constexpr int Nn  = 50000;
constexpr int Ee  = 800000;
constexpr int Gg  = 512;
constexpr int Hh  = 128;
constexpr int NGg = 50;
constexpr int NIi = 6;
constexpr int TS  = 4096;           // table size
constexpr float DMAXv = 8.6603f;    // > 5*sqrt(3) = 8.660254 (pos in [0,5)^3)

typedef short bf16x8 __attribute__((ext_vector_type(8)));
typedef float f32x4  __attribute__((ext_vector_type(4)));

__device__ __forceinline__ float ssp(float v) {
    return log1pf(__expf(-fabsf(v))) + fmaxf(v, 0.0f) - 0.69314718056f;
}
__device__ __forceinline__ unsigned short f2bf(float f) {   // RNE
    unsigned int u = __float_as_uint(f);
    u += 0x7fffu + ((u >> 16) & 1u);
    return (unsigned short)(u >> 16);
}
__device__ __forceinline__ float bf2f(unsigned int h) {     // h: low 16 bits
    return __uint_as_float(h << 16);
}

// ---------------- h = emb[z]  ----------------
__global__ void k_embed(const float* __restrict__ emb, const int* __restrict__ z,
                        float* __restrict__ h) {
    int tid = blockIdx.x * 256 + threadIdx.x;   // N*128 threads exactly
    int n = tid >> 7, f = tid & 127;
    h[tid] = emb[z[n] * Hh + f];
}

// ---------------- CSR build ----------------
__global__ void k_hist(const int* __restrict__ ei, int* __restrict__ counts) {
    int e = blockIdx.x * 256 + threadIdx.x;
    if (e >= Ee) return;
    atomicAdd(&counts[ei[e]], 1);
}

__global__ __launch_bounds__(1024) void k_scan(const int* __restrict__ counts,
                                               int* __restrict__ offsets) {
    __shared__ int s[1024];
    constexpr int CH = (Nn + 1023) / 1024;
    int t = threadIdx.x;
    int beg = t * CH, end = beg + CH; if (end > Nn) end = Nn;
    int sum = 0;
    for (int i = beg; i < end; ++i) sum += counts[i];
    s[t] = sum;
    __syncthreads();
    for (int off = 1; off < 1024; off <<= 1) {
        int v = (t >= off) ? s[t - off] : 0;
        __syncthreads();
        s[t] += v;
        __syncthreads();
    }
    int base = (t == 0) ? 0 : s[t - 1];
    for (int i = beg; i < end; ++i) {
        offsets[i] = base;
        base += counts[i];
    }
    if (t == 1023) offsets[Nn] = base;
}

__global__ void k_scatter(const int* __restrict__ ei, const float* __restrict__ pos,
                          int* __restrict__ cursor, int2* __restrict__ payload,
                          float inv_step) {
    int e = blockIdx.x * 256 + threadIdx.x;
    if (e >= Ee) return;
    int r = ei[e], c = ei[Ee + e];
    float dx = pos[3 * r    ] - pos[3 * c    ];
    float dy = pos[3 * r + 1] - pos[3 * c + 1];
    float dz = pos[3 * r + 2] - pos[3 * c + 2];
    float d = sqrtf(dx * dx + dy * dy + dz * dz + 1e-12f);
    float u = d * inv_step;
    if (u > (float)(TS - 1) - 5e-4f) u = (float)(TS - 1) - 5e-4f;
    int p = atomicAdd(&cursor[r], 1);
    payload[p] = make_int2(c, __float_as_int(u));
}

// ---------------- weight packer: fp32 [128][128] -> bf16 MFMA B-fragments ----
// Layout: Wp[m][((nt*4+kk)*64 + lane)*8 + e] = bf16(W[kk*32+(lane>>4)*8+e][nt*16+(lane&15)])
__global__ void k_pack(const float* __restrict__ lin1, const float* __restrict__ lin2,
                       const float* __restrict__ lin3, short* __restrict__ Wp) {
    int o = blockIdx.x * 256 + threadIdx.x;        // 18*16384 total
    int m = o >> 14, r = o & 16383;
    int k = (r >> 7) & 127, c = r & 127;
    int i = m / 3, which = m % 3;
    const float* src = which == 0 ? lin1 : (which == 1 ? lin2 : lin3);
    float v = src[(size_t)i * 16384 + k * 128 + c];
    int nt = c >> 4, lc = c & 15, kk = k >> 5, kg = (k >> 3) & 3, e = k & 7;
    int l = kg * 16 + lc;
    Wp[(size_t)m * 16384 + ((nt * 4 + kk) * 64 + l) * 8 + e] = (short)f2bf(v);
}

// ---------------- filter table (bf16 out): 256 blocks x 16 j each ----------------
__global__ __launch_bounds__(256) void k_table(
        const float* __restrict__ w1, const float* __restrict__ b1,
        const float* __restrict__ w2, const float* __restrict__ b2,
        unsigned short* __restrict__ T, float step) {
    __shared__ float w2s[128 * 128];      // 64 KB
    __shared__ float w1s[NGg * 128];      // 25.6 KB
    __shared__ float rbf_s[2][NGg];
    __shared__ float tb[2][128];
    int tid = threadIdx.x;
    for (int i = tid; i < 128 * 128; i += 256) w2s[i] = w2[i];
    for (int i = tid; i < NGg * 128; i += 256) w1s[i] = w1[i];
    int jj = tid >> 7, f = tid & 127;
    float bb1 = b1[f], bb2 = b2[f];
    for (int p = 0; p < 8; ++p) {
        int j = blockIdx.x * 16 + p * 2 + jj;
        float dj = j * step;
        __syncthreads();
        if (f < NGg) {
            float u = dj - f * (10.0f / 49.0f);
            rbf_s[jj][f] = expf(-12.00500f * u * u);   // -0.5/(10/49)^2
        }
        __syncthreads();
        float u = bb1;
        for (int g = 0; g < NGg; ++g)
            u = fmaf(rbf_s[jj][g], w1s[g * 128 + f], u);
        tb[jj][f] = ssp(u);
        __syncthreads();
        float w = bb2;
        for (int k = 0; k < 128; ++k)
            w = fmaf(tb[jj][k], w2s[k * 128 + f], w);
        float C = 0.5f * (cosf(dj * 0.31415926535f) + 1.0f);  // pi/10
        T[j * 128 + f] = f2bf(w * C);
    }
}

// ---------------- MFMA: x(bf16) = h @ lin1  ----------------
// 64 rows/block, 4 waves; wave w owns rows w*16..+15 (8 n-tiles of 16).
// A: LDS bf16 [64][128] XOR-swizzled (byte ^= (row&7)<<4).
// B: packed global bf16 frags, 16B/lane, L1-resident (32KB/matrix).
__global__ __launch_bounds__(256) void k_mfma1(
        const float* __restrict__ in, const short* __restrict__ Wp,
        unsigned short* __restrict__ out, int nrows) {
    __shared__ short As[64 * 128];
    int tid = threadIdx.x;
    int base = blockIdx.x * 64;
    const float4* in4 = (const float4*)(in + (size_t)base * 128);
    int lim4 = (nrows - base) * 32;
    for (int i = tid; i < 2048; i += 256) {
        float4 v = make_float4(0.f, 0.f, 0.f, 0.f);
        if (i < lim4) v = in4[i];
        ushort4 o; o.x = f2bf(v.x); o.y = f2bf(v.y); o.z = f2bf(v.z); o.w = f2bf(v.w);
        int row = i >> 5, colg = i & 31;
        int byte = (row * 256 + colg * 8) ^ ((row & 7) << 4);
        *(ushort4*)((char*)As + byte) = o;
    }
    __syncthreads();

    int w = tid >> 6, lane = tid & 63;
    int arow = w * 16 + (lane & 15);
    bf16x8 a[4];
    #pragma unroll
    for (int kk = 0; kk < 4; ++kk) {
        int byte = (arow * 256 + kk * 64 + (lane >> 4) * 16) ^ ((arow & 7) << 4);
        a[kk] = *(const bf16x8*)((const char*)As + byte);
    }
    f32x4 acc[8];
    f32x4 zero = {0.f, 0.f, 0.f, 0.f};
    #pragma unroll
    for (int nt = 0; nt < 8; ++nt) acc[nt] = zero;
    const bf16x8* Wp8 = (const bf16x8*)Wp;
    #pragma unroll
    for (int nt = 0; nt < 8; ++nt)
        #pragma unroll
        for (int kk = 0; kk < 4; ++kk)
            acc[nt] = __builtin_amdgcn_mfma_f32_16x16x32_bf16(
                a[kk], Wp8[(nt * 4 + kk) * 64 + lane], acc[nt], 0, 0, 0);
    #pragma unroll
    for (int nt = 0; nt < 8; ++nt) {
        int col = nt * 16 + (lane & 15);
        #pragma unroll
        for (int r = 0; r < 4; ++r) {
            int row = base + w * 16 + (lane >> 4) * 4 + r;
            if (row < nrows) out[(size_t)row * 128 + col] = f2bf(acc[nt][r]);
        }
    }
}

// ---------------- MFMA fused: h += ssp(agg@lin2+b2) @ lin3 + b3 ----------------
__global__ __launch_bounds__(256) void k_mfma23(
        const float* __restrict__ agg, const short* __restrict__ W2p,
        const float* __restrict__ b2, const short* __restrict__ W3p,
        const float* __restrict__ b3, float* __restrict__ h, int nrows) {
    __shared__ short As[64 * 128];
    int tid = threadIdx.x;
    int base = blockIdx.x * 64;
    const float4* in4 = (const float4*)(agg + (size_t)base * 128);
    int lim4 = (nrows - base) * 32;
    for (int i = tid; i < 2048; i += 256) {
        float4 v = make_float4(0.f, 0.f, 0.f, 0.f);
        if (i < lim4) v = in4[i];
        ushort4 o; o.x = f2bf(v.x); o.y = f2bf(v.y); o.z = f2bf(v.z); o.w = f2bf(v.w);
        int row = i >> 5, colg = i & 31;
        int byte = (row * 256 + colg * 8) ^ ((row & 7) << 4);
        *(ushort4*)((char*)As + byte) = o;
    }
    __syncthreads();

    int w = tid >> 6, lane = tid & 63;
    int arow = w * 16 + (lane & 15);
    f32x4 zero = {0.f, 0.f, 0.f, 0.f};
    bf16x8 a[4];
    #pragma unroll
    for (int kk = 0; kk < 4; ++kk) {
        int byte = (arow * 256 + kk * 64 + (lane >> 4) * 16) ^ ((arow & 7) << 4);
        a[kk] = *(const bf16x8*)((const char*)As + byte);
    }
    f32x4 acc[8];
    #pragma unroll
    for (int nt = 0; nt < 8; ++nt) acc[nt] = zero;
    const bf16x8* W2p8 = (const bf16x8*)W2p;
    #pragma unroll
    for (int nt = 0; nt < 8; ++nt)
        #pragma unroll
        for (int kk = 0; kk < 4; ++kk)
            acc[nt] = __builtin_amdgcn_mfma_f32_16x16x32_bf16(
                a[kk], W2p8[(nt * 4 + kk) * 64 + lane], acc[nt], 0, 0, 0);

    // t = ssp(acc + b2) -> back into the (consumed) LDS tile, same swizzle
    #pragma unroll
    for (int nt = 0; nt < 8; ++nt) {
        int col = nt * 16 + (lane & 15);
        float bv = b2[col];
        #pragma unroll
        for (int r = 0; r < 4; ++r) {
            int row = w * 16 + (lane >> 4) * 4 + r;
            int byte = (row * 256 + col * 2) ^ ((row & 7) << 4);
            *(unsigned short*)((char*)As + byte) = f2bf(ssp(acc[nt][r] + bv));
        }
    }
    __syncthreads();

    bf16x8 a2[4];
    #pragma unroll
    for (int kk = 0; kk < 4; ++kk) {
        int byte = (arow * 256 + kk * 64 + (lane >> 4) * 16) ^ ((arow & 7) << 4);
        a2[kk] = *(const bf16x8*)((const char*)As + byte);
    }
    f32x4 acc2[8];
    #pragma unroll
    for (int nt = 0; nt < 8; ++nt) acc2[nt] = zero;
    const bf16x8* W3p8 = (const bf16x8*)W3p;
    #pragma unroll
    for (int nt = 0; nt < 8; ++nt)
        #pragma unroll
        for (int kk = 0; kk < 4; ++kk)
            acc2[nt] = __builtin_amdgcn_mfma_f32_16x16x32_bf16(
                a2[kk], W3p8[(nt * 4 + kk) * 64 + lane], acc2[nt], 0, 0, 0);

    #pragma unroll
    for (int nt = 0; nt < 8; ++nt) {
        int col = nt * 16 + (lane & 15);
        float bv3 = b3[col];
        #pragma unroll
        for (int r = 0; r < 4; ++r) {
            int row = base + w * 16 + (lane >> 4) * 4 + r;
            if (row < nrows) {
                float* hp = h + (size_t)row * 128 + col;
                *hp += acc2[nt][r] + bv3;
            }
        }
    }
}

// ---------------- aggregation: 1 wave/node, bf16 gather + lerp, fp32 acc ----------------
__global__ __launch_bounds__(256) void k_agg(
        const int* __restrict__ offs, const int2* __restrict__ payload,
        const unsigned int* __restrict__ xw, const unsigned int* __restrict__ Tw,
        float* __restrict__ agg) {
    int wid = threadIdx.x >> 6, lane = threadIdx.x & 63;
    int n = blockIdx.x * 4 + wid;
    int beg = offs[n], end = offs[n + 1];
    float2 acc = make_float2(0.f, 0.f);
    if (beg < end) {
        int2 pl = payload[beg];
        for (int e = beg; e < end; ++e) {
            int2 cur = pl;
            if (e + 1 < end) pl = payload[e + 1];   // prefetch
            int col = cur.x;
            float u = __int_as_float(cur.y);
            int j = (int)u;
            float fr = u - (float)j;
            unsigned int t0 = Tw[j * 64 + lane];
            unsigned int t1 = Tw[j * 64 + 64 + lane];
            unsigned int xv = xw[(size_t)col * 64 + lane];
            float t0a = bf2f(t0 & 0xffffu), t0b = bf2f(t0 >> 16);
            float t1a = bf2f(t1 & 0xffffu), t1b = bf2f(t1 >> 16);
            float xa  = bf2f(xv & 0xffffu), xb  = bf2f(xv >> 16);
            acc.x = fmaf(xa, fmaf(t1a - t0a, fr, t0a), acc.x);
            acc.y = fmaf(xb, fmaf(t1b - t0b, fr, t0b), acc.y);
        }
    }
    ((float2*)agg)[(size_t)n * 64 + lane] = acc;
}

// ---------------- readout: GEMM-style per-atom MLP + segment sum ----------------
// ow1 staged in LDS (weights were streamed from global in the inner loop ->
// latency-bound at low occupancy; 91us in R5).
__global__ __launch_bounds__(256) void k_out(
        const float* __restrict__ h, const float* __restrict__ ow1,
        const float* __restrict__ ob1, const float* __restrict__ ow2,
        const float* __restrict__ ob2, const int* __restrict__ batch,
        float* __restrict__ energy, int nrows) {
    __shared__ float il[64 * 128];
    __shared__ float ws1[128 * 64];
    __shared__ float red[64 * 33];       // padded
    int tid = threadIdx.x;
    int base = blockIdx.x * 64;
    const float4* in4 = (const float4*)(h + (size_t)base * 128);
    float4* il4 = (float4*)il;
    int avail4 = (nrows - base) * 32; if (avail4 > 2048) avail4 = 2048;
    for (int i = tid; i < 2048; i += 256) {
        float4 v = make_float4(0.f, 0.f, 0.f, 0.f);
        if (i < avail4) v = in4[i];
        il4[i] = v;
        ((float4*)ws1)[i] = ((const float4*)ow1)[i];
    }
    __syncthreads();

    int rq = tid >> 5, fq = tid & 31;
    float2 acc[8];
    #pragma unroll
    for (int j = 0; j < 8; ++j) acc[j] = make_float2(0.f, 0.f);
    const float2* W2 = (const float2*)ws1;     // [128][32] float2, LDS
    for (int kk = 0; kk < 32; ++kk) {
        float2 wa = W2[(kk * 4 + 0) * 32 + fq];
        float2 wb = W2[(kk * 4 + 1) * 32 + fq];
        float2 wc = W2[(kk * 4 + 2) * 32 + fq];
        float2 wd = W2[(kk * 4 + 3) * 32 + fq];
        #pragma unroll
        for (int j = 0; j < 8; ++j) {
            float4 a = il4[(rq * 8 + j) * 32 + kk];
            acc[j].x = fmaf(a.x, wa.x, acc[j].x); acc[j].y = fmaf(a.x, wa.y, acc[j].y);
            acc[j].x = fmaf(a.y, wb.x, acc[j].x); acc[j].y = fmaf(a.y, wb.y, acc[j].y);
            acc[j].x = fmaf(a.z, wc.x, acc[j].x); acc[j].y = fmaf(a.z, wc.y, acc[j].y);
            acc[j].x = fmaf(a.w, wd.x, acc[j].x); acc[j].y = fmaf(a.w, wd.y, acc[j].y);
        }
    }
    float2 b1v = ((const float2*)ob1)[fq];
    float2 w2v = ((const float2*)ow2)[fq];
    #pragma unroll
    for (int j = 0; j < 8; ++j) {
        float pa = ssp(acc[j].x + b1v.x) * w2v.x + ssp(acc[j].y + b1v.y) * w2v.y;
        red[(rq * 8 + j) * 33 + fq] = pa;
    }
    __syncthreads();
    if (tid < 64) {
        int row = base + tid;
        if (row < nrows) {
            float s = 0.f;
            #pragma unroll
            for (int i = 0; i < 32; ++i) s += red[tid * 33 + i];
            unsafeAtomicAdd(&energy[batch[row]], s + ob2[0]);
        }
    }
}

extern "C" void kernel_launch(void* const* d_in, const int* in_sizes, int n_in,
                              void* d_out, int out_size, void* d_ws, size_t ws_size,
                              hipStream_t stream) {
    const float* pos    = (const float*)d_in[0];
    const float* emb    = (const float*)d_in[1];
    const float* w1     = (const float*)d_in[2];
    const float* b1     = (const float*)d_in[3];
    const float* w2     = (const float*)d_in[4];
    const float* b2     = (const float*)d_in[5];
    const float* lin1_w = (const float*)d_in[6];
    const float* lin2_w = (const float*)d_in[7];
    const float* lin2_b = (const float*)d_in[8];
    const float* lin_w  = (const float*)d_in[9];
    const float* lin_b  = (const float*)d_in[10];
    const float* ow1    = (const float*)d_in[11];
    const float* ob1    = (const float*)d_in[12];
    const float* ow2    = (const float*)d_in[13];
    const float* ob2    = (const float*)d_in[14];
    const int*   z      = (const int*)d_in[15];
    const int*   batch  = (const int*)d_in[16];
    const int*   ei     = (const int*)d_in[17];
    float* energy = (float*)d_out;

    char* ws = (char*)d_ws;
    float*          h       = (float*)ws;          ws += (size_t)Nn * 128 * 4;
    float*          agg     = (float*)ws;          ws += (size_t)Nn * 128 * 4;
    unsigned short* xb      = (unsigned short*)ws; ws += (size_t)Nn * 128 * 2;
    unsigned short* T       = (unsigned short*)ws; ws += (size_t)TS * 128 * 2;
    int2*           payload = (int2*)ws;           ws += (size_t)Ee * 8;
    short*          Wp      = (short*)ws;          ws += (size_t)18 * 16384 * 2;
    int*            counts  = (int*)ws;            ws += (size_t)Nn * 4;
    int*            offsets = (int*)ws;            ws += (size_t)(Nn + 1) * 4;
    int*            cursor  = (int*)ws;            ws += (size_t)Nn * 4;

    float step = DMAXv / (TS - 1);
    float inv_step = (TS - 1) / DMAXv;

    hipMemsetAsync(d_out, 0, Gg * 4, stream);
    hipMemsetAsync(counts, 0, (size_t)Nn * 4, stream);
    k_embed<<<Nn * 128 / 256, 256, 0, stream>>>(emb, z, h);

    // CSR sort of edges by target row
    k_hist<<<(Ee + 255) / 256, 256, 0, stream>>>(ei, counts);
    k_scan<<<1, 1024, 0, stream>>>(counts, offsets);
    hipMemcpyAsync(cursor, offsets, (size_t)Nn * 4, hipMemcpyDeviceToDevice, stream);
    k_scatter<<<(Ee + 255) / 256, 256, 0, stream>>>(ei, pos, cursor, payload, inv_step);

    // pack all 18 weight matrices to MFMA fragment layout (bf16)
    k_pack<<<18 * 16384 / 256, 256, 0, stream>>>(lin1_w, lin2_w, lin_w, Wp);

    int gemm_blocks = (Nn + 63) / 64;
    for (int i = 0; i < NIi; ++i) {
        const short* W1p = Wp + (size_t)(i * 3 + 0) * 16384;
        const short* W2p = Wp + (size_t)(i * 3 + 1) * 16384;
        const short* W3p = Wp + (size_t)(i * 3 + 2) * 16384;
        k_table<<<256, 256, 0, stream>>>(w1 + (size_t)i * NGg * 128, b1 + (size_t)i * 128,
                                         w2 + (size_t)i * 128 * 128, b2 + (size_t)i * 128,
                                         T, step);
        k_mfma1<<<gemm_blocks, 256, 0, stream>>>(h, W1p, xb, Nn);
        k_agg<<<Nn / 4, 256, 0, stream>>>(offsets, payload,
                                          (const unsigned int*)xb, (const unsigned int*)T, agg);
        k_mfma23<<<gemm_blocks, 256, 0, stream>>>(agg, W2p, lin2_b + (size_t)i * Hh,
                                                  W3p, lin_b + (size_t)i * Hh, h, Nn);
    }
    k_out<<<gemm_blocks, 256, 0, stream>>>(h, ow1, ob1, ow2, ob2, batch, energy, Nn);
}

// Round 10
// 1018.240 us; speedup vs baseline: 3.0032x; 1.1798x over previous
//
#include <hip/hip_runtime.h>
#include <math.h>

// SchNet forward on MI355X.
// R1: edge filter W(d)*C(d) tabulated (4096-pt lerp) -> removed 94% of FLOPs.
// R2: CSR sort (hist+scan+scatter) -> gather-only aggregation, no atomics.
// R3: x,T bf16; k_table stages weights in LDS.
// R6: node GEMMs -> MFMA bf16 16x16x32, weights packed to B-fragment layout;
//     A-tiles in XOR-swizzled LDS.
// R7: k_agg unrolled x4 (12 gathers in flight -> hide L2/L3 latency);
//     k_out -> MFMA + shfl row-reduce + sorted segmented reduce (2-3 atomics
//     per block instead of 64 same-address); k_table: bf16-packed LDS weights
//     (46KB, 3 blocks/CU) and 512 blocks x 8 j.
// R8-R10: resubmits of R7 (bench infra failures, no results; source re-audited
//     for hang/fault modes -- none found).

constexpr int Nn  = 50000;
constexpr int Ee  = 800000;
constexpr int Gg  = 512;
constexpr int Hh  = 128;
constexpr int NGg = 50;
constexpr int NIi = 6;
constexpr int TS  = 4096;           // table size
constexpr float DMAXv = 8.6603f;    // > 5*sqrt(3) = 8.660254 (pos in [0,5)^3)

typedef short bf16x8 __attribute__((ext_vector_type(8)));
typedef float f32x4  __attribute__((ext_vector_type(4)));

__device__ __forceinline__ float ssp(float v) {
    return log1pf(__expf(-fabsf(v))) + fmaxf(v, 0.0f) - 0.69314718056f;
}
__device__ __forceinline__ unsigned short f2bf(float f) {   // RNE
    unsigned int u = __float_as_uint(f);
    u += 0x7fffu + ((u >> 16) & 1u);
    return (unsigned short)(u >> 16);
}
__device__ __forceinline__ float bf2f(unsigned int h) {     // h: low 16 bits
    return __uint_as_float(h << 16);
}

// ---------------- h = emb[z]  ----------------
__global__ void k_embed(const float* __restrict__ emb, const int* __restrict__ z,
                        float* __restrict__ h) {
    int tid = blockIdx.x * 256 + threadIdx.x;   // N*128 threads exactly
    int n = tid >> 7, f = tid & 127;
    h[tid] = emb[z[n] * Hh + f];
}

// ---------------- CSR build ----------------
__global__ void k_hist(const int* __restrict__ ei, int* __restrict__ counts) {
    int e = blockIdx.x * 256 + threadIdx.x;
    if (e >= Ee) return;
    atomicAdd(&counts[ei[e]], 1);
}

__global__ __launch_bounds__(1024) void k_scan(const int* __restrict__ counts,
                                               int* __restrict__ offsets) {
    __shared__ int s[1024];
    constexpr int CH = (Nn + 1023) / 1024;
    int t = threadIdx.x;
    int beg = t * CH, end = beg + CH; if (end > Nn) end = Nn;
    int sum = 0;
    for (int i = beg; i < end; ++i) sum += counts[i];
    s[t] = sum;
    __syncthreads();
    for (int off = 1; off < 1024; off <<= 1) {
        int v = (t >= off) ? s[t - off] : 0;
        __syncthreads();
        s[t] += v;
        __syncthreads();
    }
    int base = (t == 0) ? 0 : s[t - 1];
    for (int i = beg; i < end; ++i) {
        offsets[i] = base;
        base += counts[i];
    }
    if (t == 1023) offsets[Nn] = base;
}

__global__ void k_scatter(const int* __restrict__ ei, const float* __restrict__ pos,
                          int* __restrict__ cursor, int2* __restrict__ payload,
                          float inv_step) {
    int e = blockIdx.x * 256 + threadIdx.x;
    if (e >= Ee) return;
    int r = ei[e], c = ei[Ee + e];
    float dx = pos[3 * r    ] - pos[3 * c    ];
    float dy = pos[3 * r + 1] - pos[3 * c + 1];
    float dz = pos[3 * r + 2] - pos[3 * c + 2];
    float d = sqrtf(dx * dx + dy * dy + dz * dz + 1e-12f);
    float u = d * inv_step;
    if (u > (float)(TS - 1) - 5e-4f) u = (float)(TS - 1) - 5e-4f;
    int p = atomicAdd(&cursor[r], 1);
    payload[p] = make_int2(c, __float_as_int(u));
}

// ---------------- weight packer: fp32 -> bf16 MFMA B-fragments ----------------
// 18 matrices [128][128] + ow1 [128][64].
// Frag: Wp[((nt*4+kk)*64 + l)*8 + e] = bf16(W[kk*32+(l>>4)*8+e][nt*16+(l&15)])
__global__ void k_pack(const float* __restrict__ lin1, const float* __restrict__ lin2,
                       const float* __restrict__ lin3, const float* __restrict__ ow1,
                       short* __restrict__ Wp) {
    int o = blockIdx.x * 256 + threadIdx.x;        // 18*16384 + 8192 total
    if (o < 18 * 16384) {
        int m = o >> 14, r = o & 16383;
        int k = (r >> 7) & 127, c = r & 127;
        int i = m / 3, which = m % 3;
        const float* src = which == 0 ? lin1 : (which == 1 ? lin2 : lin3);
        float v = src[(size_t)i * 16384 + k * 128 + c];
        int nt = c >> 4, lc = c & 15, kk = k >> 5, kg = (k >> 3) & 3, e = k & 7;
        int l = kg * 16 + lc;
        Wp[(size_t)m * 16384 + ((nt * 4 + kk) * 64 + l) * 8 + e] = (short)f2bf(v);
    } else {
        int r = o - 18 * 16384;                    // 0..8191
        int k = r >> 6, c = r & 63;
        float v = ow1[k * 64 + c];
        int nt = c >> 4, lc = c & 15, kk = k >> 5, kg = (k >> 3) & 3, e = k & 7;
        int l = kg * 16 + lc;
        Wp[(size_t)18 * 16384 + ((nt * 4 + kk) * 64 + l) * 8 + e] = (short)f2bf(v);
    }
}

// ---------------- filter table (bf16 out): 512 blocks x 8 j ----------------
// Weights staged as packed bf16 pairs (46KB LDS -> 3 blocks/CU).
__global__ __launch_bounds__(256) void k_table(
        const float* __restrict__ w1, const float* __restrict__ b1,
        const float* __restrict__ w2, const float* __restrict__ b2,
        unsigned short* __restrict__ T, float step) {
    __shared__ unsigned int w2p[64 * 128];   // 32 KB: (k2,f) -> bf16 pair k=2k2,2k2+1
    __shared__ unsigned int w1p[25 * 128];   // 12.5 KB
    __shared__ float rbf_s[2][NGg];
    __shared__ float tb[2][128];
    int tid = threadIdx.x;
    for (int i = tid; i < 64 * 128; i += 256) {
        int k2 = i >> 7, f = i & 127;
        unsigned int lo = f2bf(w2[(2 * k2) * 128 + f]);
        unsigned int hi = f2bf(w2[(2 * k2 + 1) * 128 + f]);
        w2p[i] = lo | (hi << 16);
    }
    for (int i = tid; i < 25 * 128; i += 256) {
        int k2 = i >> 7, f = i & 127;
        unsigned int lo = f2bf(w1[(2 * k2) * 128 + f]);
        unsigned int hi = f2bf(w1[(2 * k2 + 1) * 128 + f]);
        w1p[i] = lo | (hi << 16);
    }
    int jj = tid >> 7, f = tid & 127;
    float bb1 = b1[f], bb2 = b2[f];
    for (int p = 0; p < 4; ++p) {
        int j = blockIdx.x * 8 + p * 2 + jj;
        float dj = j * step;
        __syncthreads();                 // staging done / prev phase reads done
        if (f < NGg) {
            float u = dj - f * (10.0f / 49.0f);
            rbf_s[jj][f] = expf(-12.00500f * u * u);   // -0.5/(10/49)^2
        }
        __syncthreads();
        float u = bb1;
        for (int k2 = 0; k2 < 25; ++k2) {
            unsigned int wv = w1p[k2 * 128 + f];
            u = fmaf(rbf_s[jj][2 * k2    ], bf2f(wv & 0xffffu), u);
            u = fmaf(rbf_s[jj][2 * k2 + 1], bf2f(wv >> 16), u);
        }
        tb[jj][f] = ssp(u);
        __syncthreads();
        float w = bb2;
        for (int k2 = 0; k2 < 64; ++k2) {
            unsigned int wv = w2p[k2 * 128 + f];
            w = fmaf(tb[jj][2 * k2    ], bf2f(wv & 0xffffu), w);
            w = fmaf(tb[jj][2 * k2 + 1], bf2f(wv >> 16), w);
        }
        float C = 0.5f * (cosf(dj * 0.31415926535f) + 1.0f);  // pi/10
        T[j * 128 + f] = f2bf(w * C);
    }
}

// ---------------- MFMA: x(bf16) = h @ lin1  ----------------
__global__ __launch_bounds__(256) void k_mfma1(
        const float* __restrict__ in, const short* __restrict__ Wp,
        unsigned short* __restrict__ out, int nrows) {
    __shared__ short As[64 * 128];
    int tid = threadIdx.x;
    int base = blockIdx.x * 64;
    const float4* in4 = (const float4*)(in + (size_t)base * 128);
    int lim4 = (nrows - base) * 32;
    for (int i = tid; i < 2048; i += 256) {
        float4 v = make_float4(0.f, 0.f, 0.f, 0.f);
        if (i < lim4) v = in4[i];
        ushort4 o; o.x = f2bf(v.x); o.y = f2bf(v.y); o.z = f2bf(v.z); o.w = f2bf(v.w);
        int row = i >> 5, colg = i & 31;
        int byte = (row * 256 + colg * 8) ^ ((row & 7) << 4);
        *(ushort4*)((char*)As + byte) = o;
    }
    __syncthreads();

    int w = tid >> 6, lane = tid & 63;
    int arow = w * 16 + (lane & 15);
    bf16x8 a[4];
    #pragma unroll
    for (int kk = 0; kk < 4; ++kk) {
        int byte = (arow * 256 + kk * 64 + (lane >> 4) * 16) ^ ((arow & 7) << 4);
        a[kk] = *(const bf16x8*)((const char*)As + byte);
    }
    f32x4 acc[8];
    f32x4 zero = {0.f, 0.f, 0.f, 0.f};
    #pragma unroll
    for (int nt = 0; nt < 8; ++nt) acc[nt] = zero;
    const bf16x8* Wp8 = (const bf16x8*)Wp;
    #pragma unroll
    for (int nt = 0; nt < 8; ++nt)
        #pragma unroll
        for (int kk = 0; kk < 4; ++kk)
            acc[nt] = __builtin_amdgcn_mfma_f32_16x16x32_bf16(
                a[kk], Wp8[(nt * 4 + kk) * 64 + lane], acc[nt], 0, 0, 0);
    #pragma unroll
    for (int nt = 0; nt < 8; ++nt) {
        int col = nt * 16 + (lane & 15);
        #pragma unroll
        for (int r = 0; r < 4; ++r) {
            int row = base + w * 16 + (lane >> 4) * 4 + r;
            if (row < nrows) out[(size_t)row * 128 + col] = f2bf(acc[nt][r]);
        }
    }
}

// ---------------- MFMA fused: h += ssp(agg@lin2+b2) @ lin3 + b3 ----------------
__global__ __launch_bounds__(256) void k_mfma23(
        const float* __restrict__ agg, const short* __restrict__ W2p,
        const float* __restrict__ b2, const short* __restrict__ W3p,
        const float* __restrict__ b3, float* __restrict__ h, int nrows) {
    __shared__ short As[64 * 128];
    int tid = threadIdx.x;
    int base = blockIdx.x * 64;
    const float4* in4 = (const float4*)(agg + (size_t)base * 128);
    int lim4 = (nrows - base) * 32;
    for (int i = tid; i < 2048; i += 256) {
        float4 v = make_float4(0.f, 0.f, 0.f, 0.f);
        if (i < lim4) v = in4[i];
        ushort4 o; o.x = f2bf(v.x); o.y = f2bf(v.y); o.z = f2bf(v.z); o.w = f2bf(v.w);
        int row = i >> 5, colg = i & 31;
        int byte = (row * 256 + colg * 8) ^ ((row & 7) << 4);
        *(ushort4*)((char*)As + byte) = o;
    }
    __syncthreads();

    int w = tid >> 6, lane = tid & 63;
    int arow = w * 16 + (lane & 15);
    f32x4 zero = {0.f, 0.f, 0.f, 0.f};
    bf16x8 a[4];
    #pragma unroll
    for (int kk = 0; kk < 4; ++kk) {
        int byte = (arow * 256 + kk * 64 + (lane >> 4) * 16) ^ ((arow & 7) << 4);
        a[kk] = *(const bf16x8*)((const char*)As + byte);
    }
    f32x4 acc[8];
    #pragma unroll
    for (int nt = 0; nt < 8; ++nt) acc[nt] = zero;
    const bf16x8* W2p8 = (const bf16x8*)W2p;
    #pragma unroll
    for (int nt = 0; nt < 8; ++nt)
        #pragma unroll
        for (int kk = 0; kk < 4; ++kk)
            acc[nt] = __builtin_amdgcn_mfma_f32_16x16x32_bf16(
                a[kk], W2p8[(nt * 4 + kk) * 64 + lane], acc[nt], 0, 0, 0);

    // t = ssp(acc + b2) -> back into the (consumed) LDS tile, same swizzle
    #pragma unroll
    for (int nt = 0; nt < 8; ++nt) {
        int col = nt * 16 + (lane & 15);
        float bv = b2[col];
        #pragma unroll
        for (int r = 0; r < 4; ++r) {
            int row = w * 16 + (lane >> 4) * 4 + r;
            int byte = (row * 256 + col * 2) ^ ((row & 7) << 4);
            *(unsigned short*)((char*)As + byte) = f2bf(ssp(acc[nt][r] + bv));
        }
    }
    __syncthreads();

    bf16x8 a2[4];
    #pragma unroll
    for (int kk = 0; kk < 4; ++kk) {
        int byte = (arow * 256 + kk * 64 + (lane >> 4) * 16) ^ ((arow & 7) << 4);
        a2[kk] = *(const bf16x8*)((const char*)As + byte);
    }
    f32x4 acc2[8];
    #pragma unroll
    for (int nt = 0; nt < 8; ++nt) acc2[nt] = zero;
    const bf16x8* W3p8 = (const bf16x8*)W3p;
    #pragma unroll
    for (int nt = 0; nt < 8; ++nt)
        #pragma unroll
        for (int kk = 0; kk < 4; ++kk)
            acc2[nt] = __builtin_amdgcn_mfma_f32_16x16x32_bf16(
                a2[kk], W3p8[(nt * 4 + kk) * 64 + lane], acc2[nt], 0, 0, 0);

    #pragma unroll
    for (int nt = 0; nt < 8; ++nt) {
        int col = nt * 16 + (lane & 15);
        float bv3 = b3[col];
        #pragma unroll
        for (int r = 0; r < 4; ++r) {
            int row = base + w * 16 + (lane >> 4) * 4 + r;
            if (row < nrows) {
                float* hp = h + (size_t)row * 128 + col;
                *hp += acc2[nt][r] + bv3;
            }
        }
    }
}

// ---------------- aggregation: 1 wave/node, unroll x4 (12 gathers in flight) ----
__device__ __forceinline__ void lerp_acc(unsigned int ta, unsigned int tb,
                                         unsigned int xv, float fr, float2& acc) {
    float t0a = bf2f(ta & 0xffffu), t0b = bf2f(ta >> 16);
    float t1a = bf2f(tb & 0xffffu), t1b = bf2f(tb >> 16);
    acc.x = fmaf(bf2f(xv & 0xffffu), fmaf(t1a - t0a, fr, t0a), acc.x);
    acc.y = fmaf(bf2f(xv >> 16),     fmaf(t1b - t0b, fr, t0b), acc.y);
}

__global__ __launch_bounds__(256) void k_agg(
        const int* __restrict__ offs, const int2* __restrict__ payload,
        const unsigned int* __restrict__ xw, const unsigned int* __restrict__ Tw,
        float* __restrict__ agg) {
    int wid = threadIdx.x >> 6, lane = threadIdx.x & 63;
    int n = blockIdx.x * 4 + wid;
    int beg = offs[n], end = offs[n + 1];
    float2 acc = make_float2(0.f, 0.f);
    int e = beg, cnt = end - beg;
    int2 p0, p1, p2, p3;
    if (cnt >= 4) { p0 = payload[e]; p1 = payload[e + 1]; p2 = payload[e + 2]; p3 = payload[e + 3]; }
    while (cnt >= 4) {
        unsigned int c0 = p0.x, c1 = p1.x, c2 = p2.x, c3 = p3.x;
        float u0 = __int_as_float(p0.y), u1 = __int_as_float(p1.y);
        float u2 = __int_as_float(p2.y), u3 = __int_as_float(p3.y);
        int j0 = (int)u0, j1 = (int)u1, j2 = (int)u2, j3 = (int)u3;
        float f0 = u0 - j0, f1 = u1 - j1, f2 = u2 - j2, f3 = u3 - j3;
        // issue all 12 gathers before any FMA
        unsigned int ta0 = Tw[j0 * 64 + lane], tb0 = Tw[j0 * 64 + 64 + lane];
        unsigned int ta1 = Tw[j1 * 64 + lane], tb1 = Tw[j1 * 64 + 64 + lane];
        unsigned int ta2 = Tw[j2 * 64 + lane], tb2 = Tw[j2 * 64 + 64 + lane];
        unsigned int ta3 = Tw[j3 * 64 + lane], tb3 = Tw[j3 * 64 + 64 + lane];
        unsigned int xv0 = xw[(size_t)c0 * 64 + lane];
        unsigned int xv1 = xw[(size_t)c1 * 64 + lane];
        unsigned int xv2 = xw[(size_t)c2 * 64 + lane];
        unsigned int xv3 = xw[(size_t)c3 * 64 + lane];
        e += 4; cnt -= 4;
        if (cnt >= 4) { p0 = payload[e]; p1 = payload[e + 1]; p2 = payload[e + 2]; p3 = payload[e + 3]; }
        lerp_acc(ta0, tb0, xv0, f0, acc);
        lerp_acc(ta1, tb1, xv1, f1, acc);
        lerp_acc(ta2, tb2, xv2, f2, acc);
        lerp_acc(ta3, tb3, xv3, f3, acc);
    }
    for (; cnt > 0; --cnt, ++e) {
        int2 cur = payload[e];
        float u = __int_as_float(cur.y);
        int j = (int)u;
        float fr = u - (float)j;
        unsigned int ta = Tw[j * 64 + lane];
        unsigned int tb = Tw[j * 64 + 64 + lane];
        unsigned int xv = xw[(size_t)cur.x * 64 + lane];
        lerp_acc(ta, tb, xv, fr, acc);
    }
    ((float2*)agg)[(size_t)n * 64 + lane] = acc;
}

// ---------------- readout: MFMA per-atom MLP + sorted segmented atomics -------
__global__ __launch_bounds__(256) void k_out(
        const float* __restrict__ h, const short* __restrict__ OW1p,
        const float* __restrict__ ob1, const float* __restrict__ ow2,
        const float* __restrict__ ob2, const int* __restrict__ batch,
        float* __restrict__ energy, int nrows) {
    __shared__ short As[64 * 128];
    __shared__ float rowsum[64];
    int tid = threadIdx.x;
    int base = blockIdx.x * 64;
    const float4* in4 = (const float4*)(h + (size_t)base * 128);
    int lim4 = (nrows - base) * 32;
    for (int i = tid; i < 2048; i += 256) {
        float4 v = make_float4(0.f, 0.f, 0.f, 0.f);
        if (i < lim4) v = in4[i];
        ushort4 o; o.x = f2bf(v.x); o.y = f2bf(v.y); o.z = f2bf(v.z); o.w = f2bf(v.w);
        int row = i >> 5, colg = i & 31;
        int byte = (row * 256 + colg * 8) ^ ((row & 7) << 4);
        *(ushort4*)((char*)As + byte) = o;
    }
    __syncthreads();

    int w = tid >> 6, lane = tid & 63;
    int arow = w * 16 + (lane & 15);
    bf16x8 a[4];
    #pragma unroll
    for (int kk = 0; kk < 4; ++kk) {
        int byte = (arow * 256 + kk * 64 + (lane >> 4) * 16) ^ ((arow & 7) << 4);
        a[kk] = *(const bf16x8*)((const char*)As + byte);
    }
    f32x4 acc[4];
    f32x4 zero = {0.f, 0.f, 0.f, 0.f};
    #pragma unroll
    for (int nt = 0; nt < 4; ++nt) acc[nt] = zero;
    const bf16x8* W8 = (const bf16x8*)OW1p;
    #pragma unroll
    for (int nt = 0; nt < 4; ++nt)
        #pragma unroll
        for (int kk = 0; kk < 4; ++kk)
            acc[nt] = __builtin_amdgcn_mfma_f32_16x16x32_bf16(
                a[kk], W8[(nt * 4 + kk) * 64 + lane], acc[nt], 0, 0, 0);

    float p[4] = {0.f, 0.f, 0.f, 0.f};
    #pragma unroll
    for (int nt = 0; nt < 4; ++nt) {
        int col = nt * 16 + (lane & 15);
        float b = ob1[col], wv = ow2[col];
        #pragma unroll
        for (int r = 0; r < 4; ++r) p[r] += ssp(acc[nt][r] + b) * wv;
    }
    #pragma unroll
    for (int m = 1; m < 16; m <<= 1) {
        #pragma unroll
        for (int r = 0; r < 4; ++r) p[r] += __shfl_xor(p[r], m);
    }
    if ((lane & 15) == 0) {
        #pragma unroll
        for (int r = 0; r < 4; ++r) rowsum[w * 16 + (lane >> 4) * 4 + r] = p[r];
    }
    __syncthreads();
    if (tid < 64) {
        int row = base + tid;
        int rc = row < nrows ? row : nrows - 1;
        int g = batch[rc];
        float v = (row < nrows) ? rowsum[tid] + ob2[0] : 0.f;
        // segmented suffix reduction over sorted g (wave 0, 64 lanes)
        #pragma unroll
        for (int off = 1; off < 64; off <<= 1) {
            float vo = __shfl_down(v, off);
            int   go = __shfl_down(g, off);
            if (tid + off < 64 && go == g) v += vo;
        }
        int gp = __shfl_up(g, 1);
        if (row < nrows && (tid == 0 || gp != g))
            unsafeAtomicAdd(&energy[g], v);
    }
}

extern "C" void kernel_launch(void* const* d_in, const int* in_sizes, int n_in,
                              void* d_out, int out_size, void* d_ws, size_t ws_size,
                              hipStream_t stream) {
    const float* pos    = (const float*)d_in[0];
    const float* emb    = (const float*)d_in[1];
    const float* w1     = (const float*)d_in[2];
    const float* b1     = (const float*)d_in[3];
    const float* w2     = (const float*)d_in[4];
    const float* b2     = (const float*)d_in[5];
    const float* lin1_w = (const float*)d_in[6];
    const float* lin2_w = (const float*)d_in[7];
    const float* lin2_b = (const float*)d_in[8];
    const float* lin_w  = (const float*)d_in[9];
    const float* lin_b  = (const float*)d_in[10];
    const float* ow1    = (const float*)d_in[11];
    const float* ob1    = (const float*)d_in[12];
    const float* ow2    = (const float*)d_in[13];
    const float* ob2    = (const float*)d_in[14];
    const int*   z      = (const int*)d_in[15];
    const int*   batch  = (const int*)d_in[16];
    const int*   ei     = (const int*)d_in[17];
    float* energy = (float*)d_out;

    char* ws = (char*)d_ws;
    float*          h       = (float*)ws;          ws += (size_t)Nn * 128 * 4;
    float*          agg     = (float*)ws;          ws += (size_t)Nn * 128 * 4;
    unsigned short* xb      = (unsigned short*)ws; ws += (size_t)Nn * 128 * 2;
    unsigned short* T       = (unsigned short*)ws; ws += (size_t)TS * 128 * 2;
    int2*           payload = (int2*)ws;           ws += (size_t)Ee * 8;
    short*          Wp      = (short*)ws;          ws += ((size_t)18 * 16384 + 8192) * 2;
    int*            counts  = (int*)ws;            ws += (size_t)Nn * 4;
    int*            offsets = (int*)ws;            ws += (size_t)(Nn + 1) * 4;
    int*            cursor  = (int*)ws;            ws += (size_t)Nn * 4;

    float step = DMAXv / (TS - 1);
    float inv_step = (TS - 1) / DMAXv;

    hipMemsetAsync(d_out, 0, Gg * 4, stream);
    hipMemsetAsync(counts, 0, (size_t)Nn * 4, stream);
    k_embed<<<Nn * 128 / 256, 256, 0, stream>>>(emb, z, h);

    // CSR sort of edges by target row
    k_hist<<<(Ee + 255) / 256, 256, 0, stream>>>(ei, counts);
    k_scan<<<1, 1024, 0, stream>>>(counts, offsets);
    hipMemcpyAsync(cursor, offsets, (size_t)Nn * 4, hipMemcpyDeviceToDevice, stream);
    k_scatter<<<(Ee + 255) / 256, 256, 0, stream>>>(ei, pos, cursor, payload, inv_step);

    // pack 18 interaction matrices + ow1 to MFMA fragment layout (bf16)
    k_pack<<<(18 * 16384 + 8192) / 256, 256, 0, stream>>>(lin1_w, lin2_w, lin_w, ow1, Wp);

    int gemm_blocks = (Nn + 63) / 64;
    for (int i = 0; i < NIi; ++i) {
        const short* W1p = Wp + (size_t)(i * 3 + 0) * 16384;
        const short* W2p = Wp + (size_t)(i * 3 + 1) * 16384;
        const short* W3p = Wp + (size_t)(i * 3 + 2) * 16384;
        k_table<<<512, 256, 0, stream>>>(w1 + (size_t)i * NGg * 128, b1 + (size_t)i * 128,
                                         w2 + (size_t)i * 128 * 128, b2 + (size_t)i * 128,
                                         T, step);
        k_mfma1<<<gemm_blocks, 256, 0, stream>>>(h, W1p, xb, Nn);
        k_agg<<<Nn / 4, 256, 0, stream>>>(offsets, payload,
                                          (const unsigned int*)xb, (const unsigned int*)T, agg);
        k_mfma23<<<gemm_blocks, 256, 0, stream>>>(agg, W2p, lin2_b + (size_t)i * Hh,
                                                  W3p, lin_b + (size_t)i * Hh, h, Nn);
    }
    k_out<<<gemm_blocks, 256, 0, stream>>>(h, Wp + (size_t)18 * 16384,
                                           ob1, ow2, ob2, batch, energy, Nn);
}

// Round 12
// 949.685 us; speedup vs baseline: 3.2200x; 1.0722x over previous
//
#include <hip/hip_runtime.h>
#include <math.h>

// SchNet forward on MI355X.
// R1: edge filter W(d)*C(d) tabulated (4096-pt lerp) -> removed 94% of FLOPs.
// R2: CSR sort -> gather-only aggregation, no atomics.
// R3: x,T bf16. R6: node GEMMs -> MFMA bf16, packed B-fragments, swizzled LDS.
// R7: k_agg unroll x4; MFMA k_out + segmented atomics; bf16 k_table.
// R11: single-block k_scan (77us, 0.15% occupancy) -> 3-phase parallel scan
//      (scanA/B/C, also writes cursor -> d2d memcpy deleted);
//      k_mfma1 + k_out fused into k_fused: stage agg -> GEMM(W2)+ssp ->
//      GEMM(W3)+residual -> h_new back into same LDS tile -> third MFMA pass
//      with next iter's W1 (xb) or, on the last iter, the readout MLP.
// R12: resubmit of R11 (bench infra timeout, no result).

constexpr int Nn  = 50000;
constexpr int Ee  = 800000;
constexpr int Gg  = 512;
constexpr int Hh  = 128;
constexpr int NGg = 50;
constexpr int NIi = 6;
constexpr int TS  = 4096;           // table size
constexpr int NB  = (Nn + 255) / 256;   // 196 scan blocks
constexpr float DMAXv = 8.6603f;    // > 5*sqrt(3) = 8.660254 (pos in [0,5)^3)

typedef short bf16x8 __attribute__((ext_vector_type(8)));
typedef float f32x4  __attribute__((ext_vector_type(4)));

__device__ __forceinline__ float ssp(float v) {
    return log1pf(__expf(-fabsf(v))) + fmaxf(v, 0.0f) - 0.69314718056f;
}
__device__ __forceinline__ unsigned short f2bf(float f) {   // RNE
    unsigned int u = __float_as_uint(f);
    u += 0x7fffu + ((u >> 16) & 1u);
    return (unsigned short)(u >> 16);
}
__device__ __forceinline__ float bf2f(unsigned int h) {     // h: low 16 bits
    return __uint_as_float(h << 16);
}

// ---------------- h = emb[z]  ----------------
__global__ void k_embed(const float* __restrict__ emb, const int* __restrict__ z,
                        float* __restrict__ h) {
    int tid = blockIdx.x * 256 + threadIdx.x;   // N*128 threads exactly
    int n = tid >> 7, f = tid & 127;
    h[tid] = emb[z[n] * Hh + f];
}

// ---------------- CSR build ----------------
__global__ void k_hist(const int* __restrict__ ei, int* __restrict__ counts) {
    int e = blockIdx.x * 256 + threadIdx.x;
    if (e >= Ee) return;
    atomicAdd(&counts[ei[e]], 1);
}

// 3-phase parallel exclusive scan over counts[Nn]
__global__ __launch_bounds__(256) void k_scanA(const int* __restrict__ counts,
                                               int* __restrict__ incl,
                                               int* __restrict__ bsum) {
    int t = blockIdx.x * 256 + threadIdx.x;
    int lane = threadIdx.x & 63, wv = threadIdx.x >> 6;
    int c = (t < Nn) ? counts[t] : 0;
    int v = c;
    #pragma unroll
    for (int off = 1; off < 64; off <<= 1) {
        int u = __shfl_up(v, off);
        if (lane >= off) v += u;
    }
    __shared__ int ws[4];
    if (lane == 63) ws[wv] = v;
    __syncthreads();
    if (threadIdx.x == 0) {
        int s = 0;
        #pragma unroll
        for (int i = 0; i < 4; ++i) { int x = ws[i]; ws[i] = s; s += x; }
        bsum[blockIdx.x] = s;
    }
    __syncthreads();
    v += ws[wv];
    if (t < Nn) incl[t] = v;            // block-inclusive prefix
}

__global__ __launch_bounds__(256) void k_scanB(int* __restrict__ bsum) {
    __shared__ int s[256];
    int t = threadIdx.x;
    int v = (t < NB) ? bsum[t] : 0;
    s[t] = v;
    __syncthreads();
    for (int off = 1; off < 256; off <<= 1) {
        int u = (t >= off) ? s[t - off] : 0;
        __syncthreads();
        s[t] += u;
        __syncthreads();
    }
    if (t < NB) bsum[t] = s[t] - v;     // exclusive block base
}

__global__ __launch_bounds__(256) void k_scanC(const int* __restrict__ counts,
                                               const int* __restrict__ incl,
                                               const int* __restrict__ bsum,
                                               int* __restrict__ offsets,
                                               int* __restrict__ cursor) {
    int t = blockIdx.x * 256 + threadIdx.x;
    if (t >= Nn) return;
    int off = bsum[blockIdx.x] + incl[t] - counts[t];
    offsets[t] = off;
    cursor[t]  = off;
    if (t == Nn - 1) offsets[Nn] = off + counts[t];
}

__global__ void k_scatter(const int* __restrict__ ei, const float* __restrict__ pos,
                          int* __restrict__ cursor, int2* __restrict__ payload,
                          float inv_step) {
    int e = blockIdx.x * 256 + threadIdx.x;
    if (e >= Ee) return;
    int r = ei[e], c = ei[Ee + e];
    float dx = pos[3 * r    ] - pos[3 * c    ];
    float dy = pos[3 * r + 1] - pos[3 * c + 1];
    float dz = pos[3 * r + 2] - pos[3 * c + 2];
    float d = sqrtf(dx * dx + dy * dy + dz * dz + 1e-12f);
    float u = d * inv_step;
    if (u > (float)(TS - 1) - 5e-4f) u = (float)(TS - 1) - 5e-4f;
    int p = atomicAdd(&cursor[r], 1);
    payload[p] = make_int2(c, __float_as_int(u));
}

// ---------------- weight packer: fp32 -> bf16 MFMA B-fragments ----------------
// 18 matrices [128][128] + ow1 [128][64].
// Frag: Wp[((nt*4+kk)*64 + l)*8 + e] = bf16(W[kk*32+(l>>4)*8+e][nt*16+(l&15)])
__global__ void k_pack(const float* __restrict__ lin1, const float* __restrict__ lin2,
                       const float* __restrict__ lin3, const float* __restrict__ ow1,
                       short* __restrict__ Wp) {
    int o = blockIdx.x * 256 + threadIdx.x;        // 18*16384 + 8192 total
    if (o < 18 * 16384) {
        int m = o >> 14, r = o & 16383;
        int k = (r >> 7) & 127, c = r & 127;
        int i = m / 3, which = m % 3;
        const float* src = which == 0 ? lin1 : (which == 1 ? lin2 : lin3);
        float v = src[(size_t)i * 16384 + k * 128 + c];
        int nt = c >> 4, lc = c & 15, kk = k >> 5, kg = (k >> 3) & 3, e = k & 7;
        int l = kg * 16 + lc;
        Wp[(size_t)m * 16384 + ((nt * 4 + kk) * 64 + l) * 8 + e] = (short)f2bf(v);
    } else {
        int r = o - 18 * 16384;                    // 0..8191
        int k = r >> 6, c = r & 63;
        float v = ow1[k * 64 + c];
        int nt = c >> 4, lc = c & 15, kk = k >> 5, kg = (k >> 3) & 3, e = k & 7;
        int l = kg * 16 + lc;
        Wp[(size_t)18 * 16384 + ((nt * 4 + kk) * 64 + l) * 8 + e] = (short)f2bf(v);
    }
}

// ---------------- filter table (bf16 out): 512 blocks x 8 j ----------------
__global__ __launch_bounds__(256) void k_table(
        const float* __restrict__ w1, const float* __restrict__ b1,
        const float* __restrict__ w2, const float* __restrict__ b2,
        unsigned short* __restrict__ T, float step) {
    __shared__ unsigned int w2p[64 * 128];   // 32 KB: (k2,f) -> bf16 pair
    __shared__ unsigned int w1p[25 * 128];   // 12.5 KB
    __shared__ float rbf_s[2][NGg];
    __shared__ float tb[2][128];
    int tid = threadIdx.x;
    for (int i = tid; i < 64 * 128; i += 256) {
        int k2 = i >> 7, f = i & 127;
        unsigned int lo = f2bf(w2[(2 * k2) * 128 + f]);
        unsigned int hi = f2bf(w2[(2 * k2 + 1) * 128 + f]);
        w2p[i] = lo | (hi << 16);
    }
    for (int i = tid; i < 25 * 128; i += 256) {
        int k2 = i >> 7, f = i & 127;
        unsigned int lo = f2bf(w1[(2 * k2) * 128 + f]);
        unsigned int hi = f2bf(w1[(2 * k2 + 1) * 128 + f]);
        w1p[i] = lo | (hi << 16);
    }
    int jj = tid >> 7, f = tid & 127;
    float bb1 = b1[f], bb2 = b2[f];
    for (int p = 0; p < 4; ++p) {
        int j = blockIdx.x * 8 + p * 2 + jj;
        float dj = j * step;
        __syncthreads();
        if (f < NGg) {
            float u = dj - f * (10.0f / 49.0f);
            rbf_s[jj][f] = expf(-12.00500f * u * u);   // -0.5/(10/49)^2
        }
        __syncthreads();
        float u = bb1;
        for (int k2 = 0; k2 < 25; ++k2) {
            unsigned int wv = w1p[k2 * 128 + f];
            u = fmaf(rbf_s[jj][2 * k2    ], bf2f(wv & 0xffffu), u);
            u = fmaf(rbf_s[jj][2 * k2 + 1], bf2f(wv >> 16), u);
        }
        tb[jj][f] = ssp(u);
        __syncthreads();
        float w = bb2;
        for (int k2 = 0; k2 < 64; ++k2) {
            unsigned int wv = w2p[k2 * 128 + f];
            w = fmaf(tb[jj][2 * k2    ], bf2f(wv & 0xffffu), w);
            w = fmaf(tb[jj][2 * k2 + 1], bf2f(wv >> 16), w);
        }
        float C = 0.5f * (cosf(dj * 0.31415926535f) + 1.0f);  // pi/10
        T[j * 128 + f] = f2bf(w * C);
    }
}

// ---------------- MFMA: x(bf16) = h @ lin1 (first iteration only) -------------
__global__ __launch_bounds__(256) void k_mfma1(
        const float* __restrict__ in, const short* __restrict__ Wp,
        unsigned short* __restrict__ out, int nrows) {
    __shared__ short As[64 * 128];
    int tid = threadIdx.x;
    int base = blockIdx.x * 64;
    const float4* in4 = (const float4*)(in + (size_t)base * 128);
    int lim4 = (nrows - base) * 32;
    for (int i = tid; i < 2048; i += 256) {
        float4 v = make_float4(0.f, 0.f, 0.f, 0.f);
        if (i < lim4) v = in4[i];
        ushort4 o; o.x = f2bf(v.x); o.y = f2bf(v.y); o.z = f2bf(v.z); o.w = f2bf(v.w);
        int row = i >> 5, colg = i & 31;
        int byte = (row * 256 + colg * 8) ^ ((row & 7) << 4);
        *(ushort4*)((char*)As + byte) = o;
    }
    __syncthreads();

    int w = tid >> 6, lane = tid & 63;
    int arow = w * 16 + (lane & 15);
    bf16x8 a[4];
    #pragma unroll
    for (int kk = 0; kk < 4; ++kk) {
        int byte = (arow * 256 + kk * 64 + (lane >> 4) * 16) ^ ((arow & 7) << 4);
        a[kk] = *(const bf16x8*)((const char*)As + byte);
    }
    f32x4 acc[8];
    f32x4 zero = {0.f, 0.f, 0.f, 0.f};
    #pragma unroll
    for (int nt = 0; nt < 8; ++nt) acc[nt] = zero;
    const bf16x8* Wp8 = (const bf16x8*)Wp;
    #pragma unroll
    for (int nt = 0; nt < 8; ++nt)
        #pragma unroll
        for (int kk = 0; kk < 4; ++kk)
            acc[nt] = __builtin_amdgcn_mfma_f32_16x16x32_bf16(
                a[kk], Wp8[(nt * 4 + kk) * 64 + lane], acc[nt], 0, 0, 0);
    #pragma unroll
    for (int nt = 0; nt < 8; ++nt) {
        int col = nt * 16 + (lane & 15);
        #pragma unroll
        for (int r = 0; r < 4; ++r) {
            int row = base + w * 16 + (lane >> 4) * 4 + r;
            if (row < nrows) out[(size_t)row * 128 + col] = f2bf(acc[nt][r]);
        }
    }
}

// ---------------- fused interaction tail -------------------------------------
// h_new = h + ssp(agg@W2+b2)@W3 + b3 ; then EITHER x_next = h_new@Wnext (bf16
// to xb) OR (last iter) readout: ssp(h_new@OW1+ob1)*ow2 row-sum -> energy.
__global__ __launch_bounds__(256) void k_fused(
        const float* __restrict__ agg, const short* __restrict__ W2p,
        const float* __restrict__ b2, const short* __restrict__ W3p,
        const float* __restrict__ b3, float* __restrict__ h,
        const short* __restrict__ Wnext, unsigned short* __restrict__ xb,
        const short* __restrict__ OW1p, const float* __restrict__ ob1,
        const float* __restrict__ ow2, const float* __restrict__ ob2,
        const int* __restrict__ batch, float* __restrict__ energy, int nrows) {
    __shared__ short As[64 * 128];
    __shared__ float rowsum[64];
    int tid = threadIdx.x;
    int base = blockIdx.x * 64;
    const float4* in4 = (const float4*)(agg + (size_t)base * 128);
    int lim4 = (nrows - base) * 32;
    for (int i = tid; i < 2048; i += 256) {
        float4 v = make_float4(0.f, 0.f, 0.f, 0.f);
        if (i < lim4) v = in4[i];
        ushort4 o; o.x = f2bf(v.x); o.y = f2bf(v.y); o.z = f2bf(v.z); o.w = f2bf(v.w);
        int row = i >> 5, colg = i & 31;
        int byte = (row * 256 + colg * 8) ^ ((row & 7) << 4);
        *(ushort4*)((char*)As + byte) = o;
    }
    __syncthreads();

    int w = tid >> 6, lane = tid & 63;
    int arow = w * 16 + (lane & 15);
    f32x4 zero = {0.f, 0.f, 0.f, 0.f};
    bf16x8 a[4];
    #pragma unroll
    for (int kk = 0; kk < 4; ++kk) {
        int byte = (arow * 256 + kk * 64 + (lane >> 4) * 16) ^ ((arow & 7) << 4);
        a[kk] = *(const bf16x8*)((const char*)As + byte);
    }
    f32x4 acc[8];
    #pragma unroll
    for (int nt = 0; nt < 8; ++nt) acc[nt] = zero;
    const bf16x8* W2p8 = (const bf16x8*)W2p;
    #pragma unroll
    for (int nt = 0; nt < 8; ++nt)
        #pragma unroll
        for (int kk = 0; kk < 4; ++kk)
            acc[nt] = __builtin_amdgcn_mfma_f32_16x16x32_bf16(
                a[kk], W2p8[(nt * 4 + kk) * 64 + lane], acc[nt], 0, 0, 0);

    // t = ssp(acc + b2) -> back into own 16-row stripe of the LDS tile
    #pragma unroll
    for (int nt = 0; nt < 8; ++nt) {
        int col = nt * 16 + (lane & 15);
        float bv = b2[col];
        #pragma unroll
        for (int r = 0; r < 4; ++r) {
            int row = w * 16 + (lane >> 4) * 4 + r;
            int byte = (row * 256 + col * 2) ^ ((row & 7) << 4);
            *(unsigned short*)((char*)As + byte) = f2bf(ssp(acc[nt][r] + bv));
        }
    }
    __syncthreads();

    bf16x8 a2[4];
    #pragma unroll
    for (int kk = 0; kk < 4; ++kk) {
        int byte = (arow * 256 + kk * 64 + (lane >> 4) * 16) ^ ((arow & 7) << 4);
        a2[kk] = *(const bf16x8*)((const char*)As + byte);
    }
    f32x4 acc2[8];
    #pragma unroll
    for (int nt = 0; nt < 8; ++nt) acc2[nt] = zero;
    const bf16x8* W3p8 = (const bf16x8*)W3p;
    #pragma unroll
    for (int nt = 0; nt < 8; ++nt)
        #pragma unroll
        for (int kk = 0; kk < 4; ++kk)
            acc2[nt] = __builtin_amdgcn_mfma_f32_16x16x32_bf16(
                a2[kk], W3p8[(nt * 4 + kk) * 64 + lane], acc2[nt], 0, 0, 0);

    bool last = (OW1p != nullptr);
    // h_new = h_old + acc2 + b3: write global (except last iter, where h is
    // dead) and write bf16 into own LDS stripe for the third GEMM pass.
    #pragma unroll
    for (int nt = 0; nt < 8; ++nt) {
        int col = nt * 16 + (lane & 15);
        float bv3 = b3[col];
        #pragma unroll
        for (int r = 0; r < 4; ++r) {
            int lrow = w * 16 + (lane >> 4) * 4 + r;
            int row = base + lrow;
            float hv = 0.f;
            if (row < nrows) hv = h[(size_t)row * 128 + col];
            float nv = hv + acc2[nt][r] + bv3;
            if (!last && row < nrows) h[(size_t)row * 128 + col] = nv;
            int byte = (lrow * 256 + col * 2) ^ ((lrow & 7) << 4);
            *(unsigned short*)((char*)As + byte) = f2bf(nv);
        }
    }
    __syncthreads();

    bf16x8 a3[4];
    #pragma unroll
    for (int kk = 0; kk < 4; ++kk) {
        int byte = (arow * 256 + kk * 64 + (lane >> 4) * 16) ^ ((arow & 7) << 4);
        a3[kk] = *(const bf16x8*)((const char*)As + byte);
    }

    if (!last) {
        // x_next = h_new @ Wnext -> xb (bf16)
        f32x4 acc3[8];
        #pragma unroll
        for (int nt = 0; nt < 8; ++nt) acc3[nt] = zero;
        const bf16x8* Wn8 = (const bf16x8*)Wnext;
        #pragma unroll
        for (int nt = 0; nt < 8; ++nt)
            #pragma unroll
            for (int kk = 0; kk < 4; ++kk)
                acc3[nt] = __builtin_amdgcn_mfma_f32_16x16x32_bf16(
                    a3[kk], Wn8[(nt * 4 + kk) * 64 + lane], acc3[nt], 0, 0, 0);
        #pragma unroll
        for (int nt = 0; nt < 8; ++nt) {
            int col = nt * 16 + (lane & 15);
            #pragma unroll
            for (int r = 0; r < 4; ++r) {
                int row = base + w * 16 + (lane >> 4) * 4 + r;
                if (row < nrows) xb[(size_t)row * 128 + col] = f2bf(acc3[nt][r]);
            }
        }
    } else {
        // readout: p = ssp(h_new @ OW1 + ob1) . ow2, segment-sum by batch
        f32x4 acc4[4];
        #pragma unroll
        for (int nt = 0; nt < 4; ++nt) acc4[nt] = zero;
        const bf16x8* W8 = (const bf16x8*)OW1p;
        #pragma unroll
        for (int nt = 0; nt < 4; ++nt)
            #pragma unroll
            for (int kk = 0; kk < 4; ++kk)
                acc4[nt] = __builtin_amdgcn_mfma_f32_16x16x32_bf16(
                    a3[kk], W8[(nt * 4 + kk) * 64 + lane], acc4[nt], 0, 0, 0);
        float p[4] = {0.f, 0.f, 0.f, 0.f};
        #pragma unroll
        for (int nt = 0; nt < 4; ++nt) {
            int col = nt * 16 + (lane & 15);
            float b = ob1[col], wv = ow2[col];
            #pragma unroll
            for (int r = 0; r < 4; ++r) p[r] += ssp(acc4[nt][r] + b) * wv;
        }
        #pragma unroll
        for (int m = 1; m < 16; m <<= 1) {
            #pragma unroll
            for (int r = 0; r < 4; ++r) p[r] += __shfl_xor(p[r], m);
        }
        if ((lane & 15) == 0) {
            #pragma unroll
            for (int r = 0; r < 4; ++r) rowsum[w * 16 + (lane >> 4) * 4 + r] = p[r];
        }
        __syncthreads();
        if (tid < 64) {
            int row = base + tid;
            int rc = row < nrows ? row : nrows - 1;
            int g = batch[rc];
            float v = (row < nrows) ? rowsum[tid] + ob2[0] : 0.f;
            #pragma unroll
            for (int off = 1; off < 64; off <<= 1) {
                float vo = __shfl_down(v, off);
                int   go = __shfl_down(g, off);
                if (tid + off < 64 && go == g) v += vo;
            }
            int gp = __shfl_up(g, 1);
            if (row < nrows && (tid == 0 || gp != g))
                unsafeAtomicAdd(&energy[g], v);
        }
    }
}

// ---------------- aggregation: 1 wave/node, unroll x4 (12 gathers in flight) ----
__device__ __forceinline__ void lerp_acc(unsigned int ta, unsigned int tb,
                                         unsigned int xv, float fr, float2& acc) {
    float t0a = bf2f(ta & 0xffffu), t0b = bf2f(ta >> 16);
    float t1a = bf2f(tb & 0xffffu), t1b = bf2f(tb >> 16);
    acc.x = fmaf(bf2f(xv & 0xffffu), fmaf(t1a - t0a, fr, t0a), acc.x);
    acc.y = fmaf(bf2f(xv >> 16),     fmaf(t1b - t0b, fr, t0b), acc.y);
}

__global__ __launch_bounds__(256) void k_agg(
        const int* __restrict__ offs, const int2* __restrict__ payload,
        const unsigned int* __restrict__ xw, const unsigned int* __restrict__ Tw,
        float* __restrict__ agg) {
    int wid = threadIdx.x >> 6, lane = threadIdx.x & 63;
    int n = blockIdx.x * 4 + wid;
    int beg = offs[n], end = offs[n + 1];
    float2 acc = make_float2(0.f, 0.f);
    int e = beg, cnt = end - beg;
    int2 p0, p1, p2, p3;
    if (cnt >= 4) { p0 = payload[e]; p1 = payload[e + 1]; p2 = payload[e + 2]; p3 = payload[e + 3]; }
    while (cnt >= 4) {
        unsigned int c0 = p0.x, c1 = p1.x, c2 = p2.x, c3 = p3.x;
        float u0 = __int_as_float(p0.y), u1 = __int_as_float(p1.y);
        float u2 = __int_as_float(p2.y), u3 = __int_as_float(p3.y);
        int j0 = (int)u0, j1 = (int)u1, j2 = (int)u2, j3 = (int)u3;
        float f0 = u0 - j0, f1 = u1 - j1, f2 = u2 - j2, f3 = u3 - j3;
        unsigned int ta0 = Tw[j0 * 64 + lane], tb0 = Tw[j0 * 64 + 64 + lane];
        unsigned int ta1 = Tw[j1 * 64 + lane], tb1 = Tw[j1 * 64 + 64 + lane];
        unsigned int ta2 = Tw[j2 * 64 + lane], tb2 = Tw[j2 * 64 + 64 + lane];
        unsigned int ta3 = Tw[j3 * 64 + lane], tb3 = Tw[j3 * 64 + 64 + lane];
        unsigned int xv0 = xw[(size_t)c0 * 64 + lane];
        unsigned int xv1 = xw[(size_t)c1 * 64 + lane];
        unsigned int xv2 = xw[(size_t)c2 * 64 + lane];
        unsigned int xv3 = xw[(size_t)c3 * 64 + lane];
        e += 4; cnt -= 4;
        if (cnt >= 4) { p0 = payload[e]; p1 = payload[e + 1]; p2 = payload[e + 2]; p3 = payload[e + 3]; }
        lerp_acc(ta0, tb0, xv0, f0, acc);
        lerp_acc(ta1, tb1, xv1, f1, acc);
        lerp_acc(ta2, tb2, xv2, f2, acc);
        lerp_acc(ta3, tb3, xv3, f3, acc);
    }
    for (; cnt > 0; --cnt, ++e) {
        int2 cur = payload[e];
        float u = __int_as_float(cur.y);
        int j = (int)u;
        float fr = u - (float)j;
        unsigned int ta = Tw[j * 64 + lane];
        unsigned int tb = Tw[j * 64 + 64 + lane];
        unsigned int xv = xw[(size_t)cur.x * 64 + lane];
        lerp_acc(ta, tb, xv, fr, acc);
    }
    ((float2*)agg)[(size_t)n * 64 + lane] = acc;
}

extern "C" void kernel_launch(void* const* d_in, const int* in_sizes, int n_in,
                              void* d_out, int out_size, void* d_ws, size_t ws_size,
                              hipStream_t stream) {
    const float* pos    = (const float*)d_in[0];
    const float* emb    = (const float*)d_in[1];
    const float* w1     = (const float*)d_in[2];
    const float* b1     = (const float*)d_in[3];
    const float* w2     = (const float*)d_in[4];
    const float* b2     = (const float*)d_in[5];
    const float* lin1_w = (const float*)d_in[6];
    const float* lin2_w = (const float*)d_in[7];
    const float* lin2_b = (const float*)d_in[8];
    const float* lin_w  = (const float*)d_in[9];
    const float* lin_b  = (const float*)d_in[10];
    const float* ow1    = (const float*)d_in[11];
    const float* ob1    = (const float*)d_in[12];
    const float* ow2    = (const float*)d_in[13];
    const float* ob2    = (const float*)d_in[14];
    const int*   z      = (const int*)d_in[15];
    const int*   batch  = (const int*)d_in[16];
    const int*   ei     = (const int*)d_in[17];
    float* energy = (float*)d_out;

    char* ws = (char*)d_ws;
    float*          h       = (float*)ws;          ws += (size_t)Nn * 128 * 4;
    float*          agg     = (float*)ws;          ws += (size_t)Nn * 128 * 4;
    unsigned short* xb      = (unsigned short*)ws; ws += (size_t)Nn * 128 * 2;
    unsigned short* T       = (unsigned short*)ws; ws += (size_t)TS * 128 * 2;
    int2*           payload = (int2*)ws;           ws += (size_t)Ee * 8;
    short*          Wp      = (short*)ws;          ws += ((size_t)18 * 16384 + 8192) * 2;
    int*            counts  = (int*)ws;            ws += (size_t)Nn * 4;
    int*            offsets = (int*)ws;            ws += (size_t)(Nn + 1) * 4;
    int*            cursor  = (int*)ws;            ws += (size_t)Nn * 4;
    int*            incl    = (int*)ws;            ws += (size_t)Nn * 4;
    int*            bsum    = (int*)ws;            ws += (size_t)256 * 4;

    float step = DMAXv / (TS - 1);
    float inv_step = (TS - 1) / DMAXv;

    hipMemsetAsync(d_out, 0, Gg * 4, stream);
    hipMemsetAsync(counts, 0, (size_t)Nn * 4, stream);
    k_embed<<<Nn * 128 / 256, 256, 0, stream>>>(emb, z, h);

    // CSR sort of edges by target row (parallel 3-phase scan)
    k_hist<<<(Ee + 255) / 256, 256, 0, stream>>>(ei, counts);
    k_scanA<<<NB, 256, 0, stream>>>(counts, incl, bsum);
    k_scanB<<<1, 256, 0, stream>>>(bsum);
    k_scanC<<<NB, 256, 0, stream>>>(counts, incl, bsum, offsets, cursor);
    k_scatter<<<(Ee + 255) / 256, 256, 0, stream>>>(ei, pos, cursor, payload, inv_step);

    // pack 18 interaction matrices + ow1 to MFMA fragment layout (bf16)
    k_pack<<<(18 * 16384 + 8192) / 256, 256, 0, stream>>>(lin1_w, lin2_w, lin_w, ow1, Wp);

    int gemm_blocks = (Nn + 63) / 64;
    const short* OWp = Wp + (size_t)18 * 16384;

    k_table<<<512, 256, 0, stream>>>(w1, b1, w2, b2, T, step);
    k_mfma1<<<gemm_blocks, 256, 0, stream>>>(h, Wp, xb, Nn);

    for (int i = 0; i < NIi; ++i) {
        const short* W2p = Wp + (size_t)(i * 3 + 1) * 16384;
        const short* W3p = Wp + (size_t)(i * 3 + 2) * 16384;
        bool last = (i == NIi - 1);
        const short* Wnext = last ? nullptr : Wp + (size_t)((i + 1) * 3) * 16384;

        k_agg<<<Nn / 4, 256, 0, stream>>>(offsets, payload,
                                          (const unsigned int*)xb, (const unsigned int*)T, agg);
        if (!last)
            k_table<<<512, 256, 0, stream>>>(w1 + (size_t)(i + 1) * NGg * 128,
                                             b1 + (size_t)(i + 1) * 128,
                                             w2 + (size_t)(i + 1) * 128 * 128,
                                             b2 + (size_t)(i + 1) * 128, T, step);
        k_fused<<<gemm_blocks, 256, 0, stream>>>(
            agg, W2p, lin2_b + (size_t)i * Hh, W3p, lin_b + (size_t)i * Hh, h,
            Wnext, xb, last ? OWp : nullptr, ob1, ow2, ob2, batch, energy, Nn);
    }
}